// Round 7
// baseline (597.009 us; speedup 1.0000x reference)
//
#include <hip/hip_runtime.h>
#include <cstdint>
#include <cstddef>

#define N_NODES 100000
#define N_EDGES 250000
#define N_GRAPHS 512
#define MTILES 782            // ceil(100000/128)
#define MPAD (MTILES * 128)   // 100096
#define SB 256
#define NBLK ((N_NODES + SB - 1) / SB)   // 391
#define GEMM_BLOCKS 3136      // 98 groups * 32 (8 xcd * 4 n-tiles); m_tile = g*8+xcd in [0,784)
#define NPB 128               // nodes per block in k_gather_pre1

using f32x4  = __attribute__((ext_vector_type(4))) float;
using bf16x8 = __attribute__((ext_vector_type(8))) short;

struct alignas(8) U16x4 { unsigned short x, y, z, w; };

__device__ __forceinline__ unsigned short f32_to_bf16(float f) {
    union { float f; uint32_t u; } v; v.f = f;
    uint32_t r = v.u + 0x7FFF + ((v.u >> 16) & 1);   // RNE
    return (unsigned short)(r >> 16);
}
__device__ __forceinline__ float bf_lo(uint32_t u) {
    union { uint32_t u; float f; } v; v.u = u << 16; return v.f;
}
__device__ __forceinline__ float bf_hi(uint32_t u) {
    union { uint32_t u; float f; } v; v.u = u & 0xFFFF0000u; return v.f;
}

__device__ __forceinline__ void async_cp16(const void* g, void* l) {
    __builtin_amdgcn_global_load_lds(
        (const __attribute__((address_space(1))) void*)g,
        (__attribute__((address_space(3))) void*)l, 16, 0, 0);
}

// ---------------- utility zero kernels ----------------
__global__ void k_zero_int(int* __restrict__ p, int n) {
    int i = blockIdx.x * 256 + threadIdx.x;
    if (i < n) p[i] = 0;
}
__global__ void k_zero_f(float* __restrict__ p, int n) {
    int i = blockIdx.x * 256 + threadIdx.x;
    if (i < n) p[i] = 0.f;
}

// ---------------- CSR build ----------------
__global__ void k_hist(const int* __restrict__ ei, int* __restrict__ counts) {
    int e = blockIdx.x * 256 + threadIdx.x;
    if (e < N_EDGES) atomicAdd(&counts[ei[N_EDGES + e]], 1);
}

// --- 3-phase parallel exclusive scan of counts -> rowptr/cursor ---
__global__ __launch_bounds__(SB) void k_blocksum(const int* __restrict__ counts,
                                                 int* __restrict__ bsum) {
    __shared__ int red[4];
    int i = blockIdx.x * SB + threadIdx.x;
    int v = (i < N_NODES) ? counts[i] : 0;
#pragma unroll
    for (int off = 1; off < 64; off <<= 1) v += __shfl_xor(v, off);
    int wave = threadIdx.x >> 6, lane = threadIdx.x & 63;
    if (lane == 0) red[wave] = v;
    __syncthreads();
    if (threadIdx.x == 0) bsum[blockIdx.x] = red[0] + red[1] + red[2] + red[3];
}

__global__ __launch_bounds__(512) void k_scan_bsum(const int* __restrict__ bsum,
                                                   int* __restrict__ bpre) {
    __shared__ int s[512];
    int t = threadIdx.x;
    int orig = (t < NBLK) ? bsum[t] : 0;
    s[t] = orig;
    __syncthreads();
    for (int off = 1; off < 512; off <<= 1) {
        int v = (t >= off) ? s[t - off] : 0;
        __syncthreads();
        s[t] += v;
        __syncthreads();
    }
    if (t < NBLK) bpre[t] = s[t] - orig;   // exclusive prefix
}

__global__ __launch_bounds__(SB) void k_scan_final(const int* __restrict__ counts,
                                                   const int* __restrict__ bpre,
                                                   int* __restrict__ rowptr,
                                                   int* __restrict__ cursor) {
    __shared__ int s[SB];
    int t = threadIdx.x;
    int i = blockIdx.x * SB + t;
    int c = (i < N_NODES) ? counts[i] : 0;
    s[t] = c;
    __syncthreads();
    for (int off = 1; off < SB; off <<= 1) {
        int v = (t >= off) ? s[t - off] : 0;
        __syncthreads();
        s[t] += v;
        __syncthreads();
    }
    int pre = bpre[blockIdx.x] + s[t] - c;
    if (i < N_NODES) { rowptr[i] = pre; cursor[i] = pre; }
    if (i == 0) rowptr[N_NODES] = N_EDGES;
}

__global__ void k_fill(const int* __restrict__ ei, int* __restrict__ cursor,
                       int* __restrict__ srcs) {
    int e = blockIdx.x * 256 + threadIdx.x;
    if (e < N_EDGES) {
        int dst = ei[N_EDGES + e];
        int p = atomicAdd(&cursor[dst], 1);
        srcs[p] = ei[e];
    }
}

// ---- bf16 MFMA GEMM: Cb[M][512] = bf16(A @ Bt^T [+ bias]), optional fused col stats ----
// BK=64, XOR-swizzled LDS banks, XCD-aware block swizzle, LDS-slab coalesced epilogue.
#define SLAB_LD 136
template <int K, bool STATS>
__global__ __launch_bounds__(256) void k_gemm_bias_stats(
    const unsigned short* __restrict__ A, const unsigned short* __restrict__ Bt,
    const float* __restrict__ bias, unsigned short* __restrict__ Cb,
    float* __restrict__ colsum, float* __restrict__ colsq, int M) {
    __shared__ __align__(16) unsigned short sh[16384];   // lA[0:8192) lB[8192:16384); epilogue slab reuses [0:4352)
    unsigned short* lA = sh;
    unsigned short* lB = sh + 8192;
    const int tid  = threadIdx.x;
    const int wave = tid >> 6, lane = tid & 63;
    // XCD swizzle: 4 n-tiles of one m-tile share b%8 -> same XCD -> shared L2 for A
    const int b = blockIdx.x;
    const int m0 = ((b >> 5) * 8 + (b & 7)) * 128;
    const int n0 = ((b & 31) >> 3) * 128;
    if (m0 >= M) return;                       // padding-only m-tiles
    const int wr = (wave >> 1) * 64;
    const int wc = (wave & 1) * 64;
    const int quad = lane >> 4, m16 = lane & 15;

    f32x4 acc[4][4] = {};

    for (int k0 = 0; k0 < K; k0 += 64) {
        __syncthreads();
#pragma unroll
        for (int t = 0; t < 4; ++t) {
            int seg = (wave * 4 + t) * 64 + lane;   // 0..1023: row = seg>>3, lds col-slot = seg&7
            int row = seg >> 3, csl = seg & 7;
            int cs  = csl ^ (row & 7);              // XOR bank swizzle (global side)
            const unsigned short* gA = A + (size_t)(m0 + row) * K + (k0 + cs * 8);
            async_cp16(gA, &lA[seg * 8]);
            const unsigned short* gB = Bt + (size_t)(n0 + row) * K + (k0 + cs * 8);
            async_cp16(gB, &lB[seg * 8]);
        }
        __syncthreads();

#pragma unroll
        for (int h = 0; h < 2; ++h) {
            bf16x8 af[4], bfr[4];
#pragma unroll
            for (int rb = 0; rb < 4; ++rb) {
                int r = wr + rb * 16 + m16;
                int g = (h * 4 + quad) ^ (r & 7);
                af[rb] = *(const bf16x8*)&lA[r * 64 + g * 8];
            }
#pragma unroll
            for (int cb = 0; cb < 4; ++cb) {
                int r = wc + cb * 16 + m16;
                int g = (h * 4 + quad) ^ (r & 7);
                bfr[cb] = *(const bf16x8*)&lB[r * 64 + g * 8];
            }
#pragma unroll
            for (int rb = 0; rb < 4; ++rb)
#pragma unroll
                for (int cb = 0; cb < 4; ++cb)
                    acc[rb][cb] = __builtin_amdgcn_mfma_f32_16x16x32_bf16(
                        af[rb], bfr[cb], acc[rb][cb], 0, 0, 0);
        }
    }

    // ---- stats phase (registers + shuffles + atomics) ----
    float bvs[4];
#pragma unroll
    for (int cb = 0; cb < 4; ++cb) {
        int col = n0 + wc + cb * 16 + m16;
        float bv = STATS ? bias[col] : 0.f;
        bvs[cb] = bv;
        if constexpr (STATS) {
            float s = 0.f, s2 = 0.f;
#pragma unroll
            for (int rb = 0; rb < 4; ++rb) {
#pragma unroll
                for (int i = 0; i < 4; ++i) {
                    int row = m0 + wr + rb * 16 + quad * 4 + i;
                    if (row < M) {
                        float v = acc[rb][cb][i] + bv;
                        s += v; s2 += v * v;
                    }
                }
            }
            s  += __shfl_xor(s, 16);   s  += __shfl_xor(s, 32);
            s2 += __shfl_xor(s2, 16);  s2 += __shfl_xor(s2, 32);
            if (quad == 0) {
                atomicAdd(&colsum[col], s);
                atomicAdd(&colsq[col], s2);
            }
        }
    }

    // ---- store phase: per rb, 32x128 bf16 slab in LDS, then coalesced 16B stores ----
#pragma unroll
    for (int rb = 0; rb < 4; ++rb) {
        __syncthreads();   // protect prior K-chunk ds_reads (rb=0) / prior slab reads (rb>0)
#pragma unroll
        for (int cb = 0; cb < 4; ++cb) {
            int scol = wc + cb * 16 + m16;
#pragma unroll
            for (int i = 0; i < 4; ++i) {
                int sr = (wave >> 1) * 16 + quad * 4 + i;
                sh[sr * SLAB_LD + scol] = f32_to_bf16(acc[rb][cb][i] + bvs[cb]);
            }
        }
        __syncthreads();
#pragma unroll
        for (int s = 0; s < 2; ++s) {
            int u = tid + s * 256;            // 512 units of 16B: 32 rows x 16 col-chunks
            int sr = u >> 4, c8 = u & 15;
            int gr = m0 + (sr >> 4) * 64 + rb * 16 + (sr & 15);
            uint4 v = *(const uint4*)&sh[sr * SLAB_LD + c8 * 8];
            *(uint4*)&Cb[(size_t)gr * 512 + n0 + c8 * 8] = v;   // rows >= M land in padding
        }
    }
}

// ---------------- weights: W[K][N] fp32 -> Wt[N][K] bf16 ----------------
__global__ void k_cvt_wt(const float* __restrict__ W, unsigned short* __restrict__ Wt,
                         int K, int N) {
    int i = blockIdx.x * 256 + threadIdx.x;
    if (i < K * N) {
        int k = i / N, n = i - k * N;
        Wt[(size_t)n * K + k] = f32_to_bf16(W[i]);
    }
}

// ---------------- emb fp32 -> bf16 (row-major copy) ----------------
__global__ void k_cvt_emb(const float* __restrict__ e, unsigned short* __restrict__ o) {
    int i = blockIdx.x * 256 + threadIdx.x;
    if (i < 1000 * 256) o[i] = f32_to_bf16(e[i]);
}

// ---------------- BN coefficients: bn(x) = a*x + c ----------------
__global__ void k_bn_coeffs(const float* __restrict__ colsum, const float* __restrict__ colsq,
                            const float* __restrict__ g, const float* __restrict__ be,
                            float* __restrict__ a, float* __restrict__ c) {
    int f = blockIdx.x * 256 + threadIdx.x;
    if (f >= 512) return;
    float mu  = colsum[f] * (1.f / N_NODES);
    float var = colsq[f] * (1.f / N_NODES) - mu * mu;
    float ai  = g[f] * rsqrtf(var + 1e-5f);
    a[f] = ai;
    c[f] = be[f] - mu * ai;
}

// ---- layer 1 (factorized): pre1[n] = b1 + sum over {n}+nbrs of embW[x[.]]; stats fused ----
// embW is 1 MB bf16 (L2-resident). Wave-uniform CSR walk -> scalar index loads.
__global__ __launch_bounds__(256) void k_gather_pre1(
    const unsigned short* __restrict__ embW, const int* __restrict__ x,
    const int* __restrict__ rowptr, const int* __restrict__ srcs,
    const float* __restrict__ b1, unsigned short* __restrict__ pre1b,
    float* __restrict__ colsum, float* __restrict__ colsq) {
    __shared__ float red[2][3][512];
    int wave = threadIdx.x >> 6, lane = threadIdx.x & 63;
    float4 bl = ((const float4*)b1)[lane * 2], bh = ((const float4*)b1)[lane * 2 + 1];
    float ssum[8] = {}, ssq[8] = {};
    int base = blockIdx.x * NPB + wave * (NPB / 4);
    for (int t = 0; t < NPB / 4; ++t) {
        int node = base + t;
        if (node >= N_NODES) break;
        float acc[8] = { bl.x, bl.y, bl.z, bl.w, bh.x, bh.y, bh.z, bh.w };
        int j0 = rowptr[node], j1 = rowptr[node + 1];
        for (int j = j0 - 1; j < j1; ++j) {
            int s = (j < j0) ? node : srcs[j];          // first iteration: identity term
            int r = x[s];
            uint4 raw = ((const uint4*)(embW + (size_t)r * 512))[lane];
            acc[0] += bf_lo(raw.x); acc[1] += bf_hi(raw.x);
            acc[2] += bf_lo(raw.y); acc[3] += bf_hi(raw.y);
            acc[4] += bf_lo(raw.z); acc[5] += bf_hi(raw.z);
            acc[6] += bf_lo(raw.w); acc[7] += bf_hi(raw.w);
        }
        U16x4 o0{ f32_to_bf16(acc[0]), f32_to_bf16(acc[1]), f32_to_bf16(acc[2]), f32_to_bf16(acc[3]) };
        U16x4 o1{ f32_to_bf16(acc[4]), f32_to_bf16(acc[5]), f32_to_bf16(acc[6]), f32_to_bf16(acc[7]) };
        ((U16x4*)pre1b)[(size_t)node * 128 + lane * 2]     = o0;
        ((U16x4*)pre1b)[(size_t)node * 128 + lane * 2 + 1] = o1;
#pragma unroll
        for (int j2 = 0; j2 < 8; ++j2) { ssum[j2] += acc[j2]; ssq[j2] += acc[j2] * acc[j2]; }
    }
    if (wave != 0) {
#pragma unroll
        for (int j2 = 0; j2 < 8; ++j2) {
            red[0][wave - 1][lane * 8 + j2] = ssum[j2];
            red[1][wave - 1][lane * 8 + j2] = ssq[j2];
        }
    }
    __syncthreads();
    if (wave == 0) {
#pragma unroll
        for (int j2 = 0; j2 < 8; ++j2) {
            int col = lane * 8 + j2;
            float s  = ssum[j2] + red[0][0][col] + red[0][1][col] + red[0][2][col];
            float s2 = ssq[j2]  + red[1][0][col] + red[1][1][col] + red[1][2][col];
            atomicAdd(&colsum[col], s);
            atomicAdd(&colsq[col], s2);
        }
    }
}

// ------- layer-2 aggregate (gather): agg2b[n] = bf16(f(pre1b[n]) + sum_j f(pre1b[src_j])) ----
__global__ __launch_bounds__(256) void k_gather2(
    const unsigned short* __restrict__ pre1b, const int* __restrict__ rowptr,
    const int* __restrict__ srcs, const float* __restrict__ a1,
    const float* __restrict__ c1, unsigned short* __restrict__ agg2b) {
    int wave = threadIdx.x >> 6, lane = threadIdx.x & 63;
    int node = blockIdx.x * 4 + wave;
    if (node >= N_NODES) return;
    float4 aa0 = ((const float4*)a1)[lane * 2], aa1 = ((const float4*)a1)[lane * 2 + 1];
    float4 cc0 = ((const float4*)c1)[lane * 2], cc1 = ((const float4*)c1)[lane * 2 + 1];
    float acc[8] = {};
    int j0 = rowptr[node], j1 = rowptr[node + 1];
    for (int j = j0 - 1; j < j1; ++j) {
        int s = (j < j0) ? node : srcs[j];          // first iteration: identity term
        uint4 raw = ((const uint4*)(pre1b + (size_t)s * 512))[lane];
        acc[0] += fmaxf(fmaf(aa0.x, bf_lo(raw.x), cc0.x), 0.f);
        acc[1] += fmaxf(fmaf(aa0.y, bf_hi(raw.x), cc0.y), 0.f);
        acc[2] += fmaxf(fmaf(aa0.z, bf_lo(raw.y), cc0.z), 0.f);
        acc[3] += fmaxf(fmaf(aa0.w, bf_hi(raw.y), cc0.w), 0.f);
        acc[4] += fmaxf(fmaf(aa1.x, bf_lo(raw.z), cc1.x), 0.f);
        acc[5] += fmaxf(fmaf(aa1.y, bf_hi(raw.z), cc1.y), 0.f);
        acc[6] += fmaxf(fmaf(aa1.z, bf_lo(raw.w), cc1.z), 0.f);
        acc[7] += fmaxf(fmaf(aa1.w, bf_hi(raw.w), cc1.w), 0.f);
    }
    U16x4 o0{ f32_to_bf16(acc[0]), f32_to_bf16(acc[1]), f32_to_bf16(acc[2]), f32_to_bf16(acc[3]) };
    U16x4 o1{ f32_to_bf16(acc[4]), f32_to_bf16(acc[5]), f32_to_bf16(acc[6]), f32_to_bf16(acc[7]) };
    ((U16x4*)agg2b)[(size_t)node * 128 + lane * 2]     = o0;
    ((U16x4*)agg2b)[(size_t)node * 128 + lane * 2 + 1] = o1;
}

// ---------------- graph segment starts from sorted batch ----------------
__global__ void k_seg_starts(const int* __restrict__ batch, int* __restrict__ starts) {
    int i = blockIdx.x * 256 + threadIdx.x;
    if (i >= N_NODES) return;
    int b = batch[i];
    if (i == 0) {
        for (int g = 0; g <= b; ++g) starts[g] = 0;
    } else {
        int p = batch[i - 1];
        for (int g = p + 1; g <= b; ++g) starts[g] = i;
    }
    if (i == N_NODES - 1) {
        for (int g = b + 1; g <= N_GRAPHS; ++g) starts[g] = N_NODES;
    }
}

// ------- pooling: pooled[g] = mean_n relu(a2*pre2b[n]+c2)  (pre2b bf16) -------
__global__ __launch_bounds__(256) void k_pool(const unsigned short* __restrict__ pre2b,
                                              const int* __restrict__ starts,
                                              const float* __restrict__ a2,
                                              const float* __restrict__ c2,
                                              float* __restrict__ pooled) {
    __shared__ float red[3 * 512];
    int g = blockIdx.x;
    int wave = threadIdx.x >> 6, lane = threadIdx.x & 63;
    int s = starts[g], e = starts[g + 1];
    float4 aa0 = ((const float4*)a2)[lane * 2], aa1 = ((const float4*)a2)[lane * 2 + 1];
    float4 cc0 = ((const float4*)c2)[lane * 2], cc1 = ((const float4*)c2)[lane * 2 + 1];
    float acc[8] = {};
    for (int n = s + wave; n < e; n += 4) {
        uint4 raw = ((const uint4*)(pre2b + (size_t)n * 512))[lane];
        acc[0] += fmaxf(fmaf(aa0.x, bf_lo(raw.x), cc0.x), 0.f);
        acc[1] += fmaxf(fmaf(aa0.y, bf_hi(raw.x), cc0.y), 0.f);
        acc[2] += fmaxf(fmaf(aa0.z, bf_lo(raw.y), cc0.z), 0.f);
        acc[3] += fmaxf(fmaf(aa0.w, bf_hi(raw.y), cc0.w), 0.f);
        acc[4] += fmaxf(fmaf(aa1.x, bf_lo(raw.z), cc1.x), 0.f);
        acc[5] += fmaxf(fmaf(aa1.y, bf_hi(raw.z), cc1.y), 0.f);
        acc[6] += fmaxf(fmaf(aa1.z, bf_lo(raw.w), cc1.z), 0.f);
        acc[7] += fmaxf(fmaf(aa1.w, bf_hi(raw.w), cc1.w), 0.f);
    }
    if (wave != 0) {
#pragma unroll
        for (int j = 0; j < 8; ++j) red[(wave - 1) * 512 + lane * 8 + j] = acc[j];
    }
    __syncthreads();
    if (wave == 0) {
#pragma unroll
        for (int j = 0; j < 8; ++j)
            acc[j] += red[lane * 8 + j] + red[512 + lane * 8 + j] + red[1024 + lane * 8 + j];
        float inv = 1.f / fmaxf((float)(e - s), 1.f);
#pragma unroll
        for (int j = 0; j < 8; ++j) pooled[(size_t)g * 512 + lane * 8 + j] = acc[j] * inv;
    }
}

// ---------------- small MLP ----------------
__global__ __launch_bounds__(256) void k_mlp1(const float* __restrict__ pooled,
                                              const float* __restrict__ Wl1,
                                              const float* __restrict__ bl1,
                                              float* __restrict__ z) {
    __shared__ float sp[512];
    int i = blockIdx.x, j = threadIdx.x;
    sp[j]       = pooled[(size_t)i * 512 + j];
    sp[j + 256] = pooled[(size_t)i * 512 + 256 + j];
    __syncthreads();
    float acc = bl1[j];
#pragma unroll 4
    for (int k = 0; k < 512; ++k) acc = fmaf(sp[k], Wl1[(size_t)k * 256 + j], acc);
    z[(size_t)i * 256 + j] = fmaxf(acc, 0.f);
}

__global__ __launch_bounds__(128) void k_mlp2(const float* __restrict__ z,
                                              const float* __restrict__ Wl2,
                                              const float* __restrict__ bl2,
                                              float* __restrict__ out) {
    __shared__ float sz[256];
    int i = blockIdx.x, j = threadIdx.x;
    sz[j]       = z[(size_t)i * 256 + j];
    sz[j + 128] = z[(size_t)i * 256 + 128 + j];
    __syncthreads();
    float acc = bl2[j];
#pragma unroll 4
    for (int k = 0; k < 256; ++k) acc = fmaf(sz[k], Wl2[(size_t)k * 128 + j], acc);
    out[(size_t)i * 128 + j] = acc;
}

extern "C" void kernel_launch(void* const* d_in, const int* in_sizes, int n_in,
                              void* d_out, int out_size, void* d_ws, size_t ws_size,
                              hipStream_t stream) {
    const int*   x    = (const int*)d_in[0];
    const int*   ei   = (const int*)d_in[1];
    const int*   batch= (const int*)d_in[2];
    const float* emb  = (const float*)d_in[3];
    const float* W1   = (const float*)d_in[4];
    const float* b1   = (const float*)d_in[5];
    const float* g1   = (const float*)d_in[6];
    const float* be1  = (const float*)d_in[7];
    const float* W2   = (const float*)d_in[8];
    const float* b2   = (const float*)d_in[9];
    const float* g2   = (const float*)d_in[10];
    const float* be2  = (const float*)d_in[11];
    const float* Wl1  = (const float*)d_in[12];
    const float* bl1  = (const float*)d_in[13];
    const float* Wl2  = (const float*)d_in[14];
    const float* bl2  = (const float*)d_in[15];
    float* out = (float*)d_out;

    char* ws = (char*)d_ws;
    size_t o = 0;
    auto alloc = [&](size_t bytes) { char* p = ws + o; o += (bytes + 255) & ~(size_t)255; return p; };

    // ---- small persistent buffers (~8 MB) ----
    unsigned short* W1tb = (unsigned short*)alloc((size_t)512 * 256 * 2);
    unsigned short* W2tb = (unsigned short*)alloc((size_t)512 * 512 * 2);
    unsigned short* embB = (unsigned short*)alloc((size_t)1024 * 256 * 2);  // emb bf16 (1024-row pad)
    unsigned short* embW = (unsigned short*)alloc((size_t)1024 * 512 * 2);  // emb @ W1, bf16
    float* sums   = (float*)alloc(4 * 512 * 4);
    float* colsum1 = sums, *colsq1 = sums + 512, *colsum2 = sums + 1024, *colsq2 = sums + 1536;
    float* coeffs = (float*)alloc(4 * 512 * 4);
    float* a1 = coeffs, *c1 = coeffs + 512, *a2 = coeffs + 1024, *c2 = coeffs + 1536;
    int*   starts = (int*)alloc((N_GRAPHS + 1) * 4);
    float* pooled = (float*)alloc((size_t)N_GRAPHS * 512 * 4);
    float* zbuf   = (float*)alloc((size_t)N_GRAPHS * 256 * 4);
    int*   counts = (int*)alloc((size_t)N_NODES * 4);
    int*   rowptr = (int*)alloc((size_t)(N_NODES + 1) * 4);
    int*   cursor = (int*)alloc((size_t)N_NODES * 4);
    int*   srcs   = (int*)alloc((size_t)N_EDGES * 4);
    int*   bsum   = (int*)alloc((size_t)NBLK * 4);
    int*   bpre   = (int*)alloc((size_t)NBLK * 4);

    // ---- slotA (102.5 MB): agg2b(bf16, MPAD*512) ----
    unsigned short* agg2b = (unsigned short*)alloc((size_t)MPAD * 512 * 2);
    // ---- slotB (102.5 MB): pre1b -> pre2b (disjoint lifetimes) ----
    char* slotB = alloc((size_t)MPAD * 512 * 2);
    unsigned short* pre1b = (unsigned short*)slotB;
    unsigned short* pre2b = (unsigned short*)slotB;
    (void)ws_size; (void)in_sizes; (void)n_in; (void)out_size;

    // ---- CSR build (parallel 3-phase scan) ----
    k_zero_int<<<(N_NODES + 255) / 256, 256, 0, stream>>>(counts, N_NODES);
    k_zero_f<<<8, 256, 0, stream>>>(sums, 2048);
    k_hist<<<(N_EDGES + 255) / 256, 256, 0, stream>>>(ei, counts);
    k_blocksum<<<NBLK, SB, 0, stream>>>(counts, bsum);
    k_scan_bsum<<<1, 512, 0, stream>>>(bsum, bpre);
    k_scan_final<<<NBLK, SB, 0, stream>>>(counts, bpre, rowptr, cursor);
    k_fill<<<(N_EDGES + 255) / 256, 256, 0, stream>>>(ei, cursor, srcs);

    // ---- weight / table prep ----
    k_cvt_wt<<<(256 * 512 + 255) / 256, 256, 0, stream>>>(W1, W1tb, 256, 512);
    k_cvt_wt<<<(512 * 512 + 255) / 256, 256, 0, stream>>>(W2, W2tb, 512, 512);
    k_cvt_emb<<<1000, 256, 0, stream>>>(emb, embB);
    // embW = emb @ W1 (1024x512, rows >=1000 garbage but never gathered)
    k_gemm_bias_stats<256, false><<<32, 256, 0, stream>>>(
        embB, W1tb, nullptr, embW, nullptr, nullptr, 1024);

    // ---- layer 1 (gather-aggregate of embW rows, stats fused) ----
    k_gather_pre1<<<(N_NODES + NPB - 1) / NPB, 256, 0, stream>>>(
        embW, x, rowptr, srcs, b1, pre1b, colsum1, colsq1);
    k_bn_coeffs<<<2, 256, 0, stream>>>(colsum1, colsq1, g1, be1, a1, c1);

    // ---- layer 2 ----
    k_gather2<<<(N_NODES + 3) / 4, 256, 0, stream>>>(pre1b, rowptr, srcs, a1, c1, agg2b);
    k_gemm_bias_stats<512, true><<<GEMM_BLOCKS, 256, 0, stream>>>(
        agg2b, W2tb, b2, pre2b, colsum2, colsq2, N_NODES);
    k_bn_coeffs<<<2, 256, 0, stream>>>(colsum2, colsq2, g2, be2, a2, c2);

    // ---- pooling + MLP ----
    k_seg_starts<<<(N_NODES + 255) / 256, 256, 0, stream>>>(batch, starts);
    k_pool<<<N_GRAPHS, 256, 0, stream>>>(pre2b, starts, a2, c2, pooled);
    k_mlp1<<<N_GRAPHS, 256, 0, stream>>>(pooled, Wl1, bl1, zbuf);
    k_mlp2<<<N_GRAPHS, 128, 0, stream>>>(zbuf, Wl2, bl2, out);
}

// Round 8
// 560.044 us; speedup vs baseline: 1.0660x; 1.0660x over previous
//
#include <hip/hip_runtime.h>
#include <cstdint>
#include <cstddef>

#define N_NODES 100000
#define N_EDGES 250000
#define N_GRAPHS 512
#define MTILES 782            // ceil(100000/128)
#define MPAD (MTILES * 128)   // 100096
#define SB 256
#define NBLK ((N_NODES + SB - 1) / SB)   // 391
#define GEMM_BLOCKS 3136      // 98 groups * 32 (8 xcd * 4 n-tiles); m_tile = g*8+xcd in [0,784)

using f32x4  = __attribute__((ext_vector_type(4))) float;
using bf16x8 = __attribute__((ext_vector_type(8))) short;

struct alignas(8) U16x4 { unsigned short x, y, z, w; };

__device__ __forceinline__ unsigned short f32_to_bf16(float f) {
    union { float f; uint32_t u; } v; v.f = f;
    uint32_t r = v.u + 0x7FFF + ((v.u >> 16) & 1);   // RNE
    return (unsigned short)(r >> 16);
}
__device__ __forceinline__ float bf_lo(uint32_t u) {
    union { uint32_t u; float f; } v; v.u = u << 16; return v.f;
}
__device__ __forceinline__ float bf_hi(uint32_t u) {
    union { uint32_t u; float f; } v; v.u = u & 0xFFFF0000u; return v.f;
}

__device__ __forceinline__ void async_cp16(const void* g, void* l) {
    __builtin_amdgcn_global_load_lds(
        (const __attribute__((address_space(1))) void*)g,
        (__attribute__((address_space(3))) void*)l, 16, 0, 0);
}

// ---------------- utility zero kernels ----------------
__global__ void k_zero_int(int* __restrict__ p, int n) {
    int i = blockIdx.x * 256 + threadIdx.x;
    if (i < n) p[i] = 0;
}
__global__ void k_zero_f(float* __restrict__ p, int n) {
    int i = blockIdx.x * 256 + threadIdx.x;
    if (i < n) p[i] = 0.f;
}

// ---------------- CSR build ----------------
__global__ void k_hist(const int* __restrict__ ei, int* __restrict__ counts) {
    int e = blockIdx.x * 256 + threadIdx.x;
    if (e < N_EDGES) atomicAdd(&counts[ei[N_EDGES + e]], 1);
}

// --- 3-phase parallel exclusive scan of counts -> rowptr/cursor ---
__global__ __launch_bounds__(SB) void k_blocksum(const int* __restrict__ counts,
                                                 int* __restrict__ bsum) {
    __shared__ int red[4];
    int i = blockIdx.x * SB + threadIdx.x;
    int v = (i < N_NODES) ? counts[i] : 0;
#pragma unroll
    for (int off = 1; off < 64; off <<= 1) v += __shfl_xor(v, off);
    int wave = threadIdx.x >> 6, lane = threadIdx.x & 63;
    if (lane == 0) red[wave] = v;
    __syncthreads();
    if (threadIdx.x == 0) bsum[blockIdx.x] = red[0] + red[1] + red[2] + red[3];
}

__global__ __launch_bounds__(512) void k_scan_bsum(const int* __restrict__ bsum,
                                                   int* __restrict__ bpre) {
    __shared__ int s[512];
    int t = threadIdx.x;
    int orig = (t < NBLK) ? bsum[t] : 0;
    s[t] = orig;
    __syncthreads();
    for (int off = 1; off < 512; off <<= 1) {
        int v = (t >= off) ? s[t - off] : 0;
        __syncthreads();
        s[t] += v;
        __syncthreads();
    }
    if (t < NBLK) bpre[t] = s[t] - orig;   // exclusive prefix
}

__global__ __launch_bounds__(SB) void k_scan_final(const int* __restrict__ counts,
                                                   const int* __restrict__ bpre,
                                                   int* __restrict__ rowptr,
                                                   int* __restrict__ cursor) {
    __shared__ int s[SB];
    int t = threadIdx.x;
    int i = blockIdx.x * SB + t;
    int c = (i < N_NODES) ? counts[i] : 0;
    s[t] = c;
    __syncthreads();
    for (int off = 1; off < SB; off <<= 1) {
        int v = (t >= off) ? s[t - off] : 0;
        __syncthreads();
        s[t] += v;
        __syncthreads();
    }
    int pre = bpre[blockIdx.x] + s[t] - c;
    if (i < N_NODES) { rowptr[i] = pre; cursor[i] = pre; }
    if (i == 0) rowptr[N_NODES] = N_EDGES;
}

__global__ void k_fill(const int* __restrict__ ei, int* __restrict__ cursor,
                       int* __restrict__ srcs) {
    int e = blockIdx.x * 256 + threadIdx.x;
    if (e < N_EDGES) {
        int dst = ei[N_EDGES + e];
        int p = atomicAdd(&cursor[dst], 1);
        srcs[p] = ei[e];
    }
}

// ---- bf16 MFMA GEMM: Cb[M][512] = bf16(A @ Bt^T [+ bias]), optional fused col stats ----
// BK=64, XOR-swizzled LDS banks, XCD-aware block swizzle, LDS-slab coalesced epilogue.
#define SLAB_LD 136
template <int K, bool STATS>
__global__ __launch_bounds__(256) void k_gemm_bias_stats(
    const unsigned short* __restrict__ A, const unsigned short* __restrict__ Bt,
    const float* __restrict__ bias, unsigned short* __restrict__ Cb,
    float* __restrict__ colsum, float* __restrict__ colsq, int M) {
    __shared__ __align__(16) unsigned short sh[16384];   // lA[0:8192) lB[8192:16384); epilogue slab reuses [0:4352)
    unsigned short* lA = sh;
    unsigned short* lB = sh + 8192;
    const int tid  = threadIdx.x;
    const int wave = tid >> 6, lane = tid & 63;
    // XCD swizzle: 4 n-tiles of one m-tile share b%8 -> same XCD -> shared L2 for A
    const int b = blockIdx.x;
    const int m0 = ((b >> 5) * 8 + (b & 7)) * 128;
    const int n0 = ((b & 31) >> 3) * 128;
    if (m0 >= M) return;                       // padding-only m-tiles
    const int wr = (wave >> 1) * 64;
    const int wc = (wave & 1) * 64;
    const int quad = lane >> 4, m16 = lane & 15;

    f32x4 acc[4][4] = {};

    for (int k0 = 0; k0 < K; k0 += 64) {
        __syncthreads();
#pragma unroll
        for (int t = 0; t < 4; ++t) {
            int seg = (wave * 4 + t) * 64 + lane;   // 0..1023: row = seg>>3, lds col-slot = seg&7
            int row = seg >> 3, csl = seg & 7;
            int cs  = csl ^ (row & 7);              // XOR bank swizzle (global side)
            const unsigned short* gA = A + (size_t)(m0 + row) * K + (k0 + cs * 8);
            async_cp16(gA, &lA[seg * 8]);
            const unsigned short* gB = Bt + (size_t)(n0 + row) * K + (k0 + cs * 8);
            async_cp16(gB, &lB[seg * 8]);
        }
        __syncthreads();

#pragma unroll
        for (int h = 0; h < 2; ++h) {
            bf16x8 af[4], bfr[4];
#pragma unroll
            for (int rb = 0; rb < 4; ++rb) {
                int r = wr + rb * 16 + m16;
                int g = (h * 4 + quad) ^ (r & 7);
                af[rb] = *(const bf16x8*)&lA[r * 64 + g * 8];
            }
#pragma unroll
            for (int cb = 0; cb < 4; ++cb) {
                int r = wc + cb * 16 + m16;
                int g = (h * 4 + quad) ^ (r & 7);
                bfr[cb] = *(const bf16x8*)&lB[r * 64 + g * 8];
            }
#pragma unroll
            for (int rb = 0; rb < 4; ++rb)
#pragma unroll
                for (int cb = 0; cb < 4; ++cb)
                    acc[rb][cb] = __builtin_amdgcn_mfma_f32_16x16x32_bf16(
                        af[rb], bfr[cb], acc[rb][cb], 0, 0, 0);
        }
    }

    // ---- stats phase (registers + shuffles + atomics) ----
    float bvs[4];
#pragma unroll
    for (int cb = 0; cb < 4; ++cb) {
        int col = n0 + wc + cb * 16 + m16;
        float bv = STATS ? bias[col] : 0.f;
        bvs[cb] = bv;
        if constexpr (STATS) {
            float s = 0.f, s2 = 0.f;
#pragma unroll
            for (int rb = 0; rb < 4; ++rb) {
#pragma unroll
                for (int i = 0; i < 4; ++i) {
                    int row = m0 + wr + rb * 16 + quad * 4 + i;
                    if (row < M) {
                        float v = acc[rb][cb][i] + bv;
                        s += v; s2 += v * v;
                    }
                }
            }
            s  += __shfl_xor(s, 16);   s  += __shfl_xor(s, 32);
            s2 += __shfl_xor(s2, 16);  s2 += __shfl_xor(s2, 32);
            if (quad == 0) {
                atomicAdd(&colsum[col], s);
                atomicAdd(&colsq[col], s2);
            }
        }
    }

    // ---- store phase: per rb, 32x128 bf16 slab in LDS, then coalesced 16B stores ----
#pragma unroll
    for (int rb = 0; rb < 4; ++rb) {
        __syncthreads();   // protect prior K-chunk ds_reads (rb=0) / prior slab reads (rb>0)
#pragma unroll
        for (int cb = 0; cb < 4; ++cb) {
            int scol = wc + cb * 16 + m16;
#pragma unroll
            for (int i = 0; i < 4; ++i) {
                int sr = (wave >> 1) * 16 + quad * 4 + i;
                sh[sr * SLAB_LD + scol] = f32_to_bf16(acc[rb][cb][i] + bvs[cb]);
            }
        }
        __syncthreads();
#pragma unroll
        for (int s = 0; s < 2; ++s) {
            int u = tid + s * 256;            // 512 units of 16B: 32 rows x 16 col-chunks
            int sr = u >> 4, c8 = u & 15;
            int gr = m0 + (sr >> 4) * 64 + rb * 16 + (sr & 15);
            uint4 v = *(const uint4*)&sh[sr * SLAB_LD + c8 * 8];
            *(uint4*)&Cb[(size_t)gr * 512 + n0 + c8 * 8] = v;   // rows >= M land in padding
        }
    }
}

// ---------------- weights: W[K][N] fp32 -> Wt[N][K] bf16 ----------------
__global__ void k_cvt_wt(const float* __restrict__ W, unsigned short* __restrict__ Wt,
                         int K, int N) {
    int i = blockIdx.x * 256 + threadIdx.x;
    if (i < K * N) {
        int k = i / N, n = i - k * N;
        Wt[(size_t)n * K + k] = f32_to_bf16(W[i]);
    }
}

// ---------------- emb fp32 -> bf16 (row-major copy) ----------------
__global__ void k_cvt_emb(const float* __restrict__ e, unsigned short* __restrict__ o) {
    int i = blockIdx.x * 256 + threadIdx.x;
    if (i < 1000 * 256) o[i] = f32_to_bf16(e[i]);
}

// ---------------- BN coefficients: bn(x) = a*x + c ----------------
__global__ void k_bn_coeffs(const float* __restrict__ colsum, const float* __restrict__ colsq,
                            const float* __restrict__ g, const float* __restrict__ be,
                            float* __restrict__ a, float* __restrict__ c) {
    int f = blockIdx.x * 256 + threadIdx.x;
    if (f >= 512) return;
    float mu  = colsum[f] * (1.f / N_NODES);
    float var = colsq[f] * (1.f / N_NODES) - mu * mu;
    float ai  = g[f] * rsqrtf(var + 1e-5f);
    a[f] = ai;
    c[f] = be[f] - mu * ai;
}

// ---- layer 1 (factorized): pre1b[n] = bf16(b1 + sum over {n}+nbrs of embW[x[.]]) ----
// embW is 1 MB bf16 (L2-resident). One node per wave (latency-hiding via 25k blocks).
__global__ __launch_bounds__(256) void k_gather_pre1(
    const unsigned short* __restrict__ embW, const int* __restrict__ x,
    const int* __restrict__ rowptr, const int* __restrict__ srcs,
    const float* __restrict__ b1, unsigned short* __restrict__ pre1b) {
    int wave = threadIdx.x >> 6, lane = threadIdx.x & 63;
    int node = blockIdx.x * 4 + wave;
    if (node >= N_NODES) return;
    float4 bl = ((const float4*)b1)[lane * 2], bh = ((const float4*)b1)[lane * 2 + 1];
    float acc[8] = { bl.x, bl.y, bl.z, bl.w, bh.x, bh.y, bh.z, bh.w };
    int j0 = rowptr[node], j1 = rowptr[node + 1];
    for (int j = j0 - 1; j < j1; ++j) {
        int s = (j < j0) ? node : srcs[j];          // first iteration: identity term
        int r = x[s];
        uint4 raw = ((const uint4*)(embW + (size_t)r * 512))[lane];
        acc[0] += bf_lo(raw.x); acc[1] += bf_hi(raw.x);
        acc[2] += bf_lo(raw.y); acc[3] += bf_hi(raw.y);
        acc[4] += bf_lo(raw.z); acc[5] += bf_hi(raw.z);
        acc[6] += bf_lo(raw.w); acc[7] += bf_hi(raw.w);
    }
    U16x4 o0{ f32_to_bf16(acc[0]), f32_to_bf16(acc[1]), f32_to_bf16(acc[2]), f32_to_bf16(acc[3]) };
    U16x4 o1{ f32_to_bf16(acc[4]), f32_to_bf16(acc[5]), f32_to_bf16(acc[6]), f32_to_bf16(acc[7]) };
    ((U16x4*)pre1b)[(size_t)node * 128 + lane * 2]     = o0;
    ((U16x4*)pre1b)[(size_t)node * 128 + lane * 2 + 1] = o1;
}

// ---- streaming column stats over bf16 matrix: 250 blocks x 400 rows, coalesced ----
__global__ __launch_bounds__(256) void k_stats1(const unsigned short* __restrict__ pre,
                                                float* __restrict__ colsum,
                                                float* __restrict__ colsq) {
    int tid = threadIdx.x;               // each thread: 2 adjacent cols (one uint)
    int r0 = blockIdx.x * 400;
    int r1 = min(r0 + 400, N_NODES);
    float s0 = 0.f, s1 = 0.f, q0 = 0.f, q1 = 0.f;
    for (int r = r0; r < r1; ++r) {
        uint32_t u = ((const uint32_t*)(pre + (size_t)r * 512))[tid];
        float v0 = bf_lo(u), v1 = bf_hi(u);
        s0 += v0; q0 += v0 * v0;
        s1 += v1; q1 += v1 * v1;
    }
    atomicAdd(&colsum[tid * 2],     s0);
    atomicAdd(&colsq[tid * 2],      q0);
    atomicAdd(&colsum[tid * 2 + 1], s1);
    atomicAdd(&colsq[tid * 2 + 1],  q1);
}

// ------- layer-2 aggregate (gather): agg2b[n] = bf16(f(pre1b[n]) + sum_j f(pre1b[src_j])) ----
__global__ __launch_bounds__(256) void k_gather2(
    const unsigned short* __restrict__ pre1b, const int* __restrict__ rowptr,
    const int* __restrict__ srcs, const float* __restrict__ a1,
    const float* __restrict__ c1, unsigned short* __restrict__ agg2b) {
    int wave = threadIdx.x >> 6, lane = threadIdx.x & 63;
    int node = blockIdx.x * 4 + wave;
    if (node >= N_NODES) return;
    float4 aa0 = ((const float4*)a1)[lane * 2], aa1 = ((const float4*)a1)[lane * 2 + 1];
    float4 cc0 = ((const float4*)c1)[lane * 2], cc1 = ((const float4*)c1)[lane * 2 + 1];
    float acc[8] = {};
    int j0 = rowptr[node], j1 = rowptr[node + 1];
    for (int j = j0 - 1; j < j1; ++j) {
        int s = (j < j0) ? node : srcs[j];          // first iteration: identity term
        uint4 raw = ((const uint4*)(pre1b + (size_t)s * 512))[lane];
        acc[0] += fmaxf(fmaf(aa0.x, bf_lo(raw.x), cc0.x), 0.f);
        acc[1] += fmaxf(fmaf(aa0.y, bf_hi(raw.x), cc0.y), 0.f);
        acc[2] += fmaxf(fmaf(aa0.z, bf_lo(raw.y), cc0.z), 0.f);
        acc[3] += fmaxf(fmaf(aa0.w, bf_hi(raw.y), cc0.w), 0.f);
        acc[4] += fmaxf(fmaf(aa1.x, bf_lo(raw.z), cc1.x), 0.f);
        acc[5] += fmaxf(fmaf(aa1.y, bf_hi(raw.z), cc1.y), 0.f);
        acc[6] += fmaxf(fmaf(aa1.z, bf_lo(raw.w), cc1.z), 0.f);
        acc[7] += fmaxf(fmaf(aa1.w, bf_hi(raw.w), cc1.w), 0.f);
    }
    U16x4 o0{ f32_to_bf16(acc[0]), f32_to_bf16(acc[1]), f32_to_bf16(acc[2]), f32_to_bf16(acc[3]) };
    U16x4 o1{ f32_to_bf16(acc[4]), f32_to_bf16(acc[5]), f32_to_bf16(acc[6]), f32_to_bf16(acc[7]) };
    ((U16x4*)agg2b)[(size_t)node * 128 + lane * 2]     = o0;
    ((U16x4*)agg2b)[(size_t)node * 128 + lane * 2 + 1] = o1;
}

// ---------------- graph segment starts from sorted batch ----------------
__global__ void k_seg_starts(const int* __restrict__ batch, int* __restrict__ starts) {
    int i = blockIdx.x * 256 + threadIdx.x;
    if (i >= N_NODES) return;
    int b = batch[i];
    if (i == 0) {
        for (int g = 0; g <= b; ++g) starts[g] = 0;
    } else {
        int p = batch[i - 1];
        for (int g = p + 1; g <= b; ++g) starts[g] = i;
    }
    if (i == N_NODES - 1) {
        for (int g = b + 1; g <= N_GRAPHS; ++g) starts[g] = N_NODES;
    }
}

// ------- pooling: pooled[g] = mean_n relu(a2*pre2b[n]+c2)  (pre2b bf16) -------
__global__ __launch_bounds__(256) void k_pool(const unsigned short* __restrict__ pre2b,
                                              const int* __restrict__ starts,
                                              const float* __restrict__ a2,
                                              const float* __restrict__ c2,
                                              float* __restrict__ pooled) {
    __shared__ float red[3 * 512];
    int g = blockIdx.x;
    int wave = threadIdx.x >> 6, lane = threadIdx.x & 63;
    int s = starts[g], e = starts[g + 1];
    float4 aa0 = ((const float4*)a2)[lane * 2], aa1 = ((const float4*)a2)[lane * 2 + 1];
    float4 cc0 = ((const float4*)c2)[lane * 2], cc1 = ((const float4*)c2)[lane * 2 + 1];
    float acc[8] = {};
    for (int n = s + wave; n < e; n += 4) {
        uint4 raw = ((const uint4*)(pre2b + (size_t)n * 512))[lane];
        acc[0] += fmaxf(fmaf(aa0.x, bf_lo(raw.x), cc0.x), 0.f);
        acc[1] += fmaxf(fmaf(aa0.y, bf_hi(raw.x), cc0.y), 0.f);
        acc[2] += fmaxf(fmaf(aa0.z, bf_lo(raw.y), cc0.z), 0.f);
        acc[3] += fmaxf(fmaf(aa0.w, bf_hi(raw.y), cc0.w), 0.f);
        acc[4] += fmaxf(fmaf(aa1.x, bf_lo(raw.z), cc1.x), 0.f);
        acc[5] += fmaxf(fmaf(aa1.y, bf_hi(raw.z), cc1.y), 0.f);
        acc[6] += fmaxf(fmaf(aa1.z, bf_lo(raw.w), cc1.z), 0.f);
        acc[7] += fmaxf(fmaf(aa1.w, bf_hi(raw.w), cc1.w), 0.f);
    }
    if (wave != 0) {
#pragma unroll
        for (int j = 0; j < 8; ++j) red[(wave - 1) * 512 + lane * 8 + j] = acc[j];
    }
    __syncthreads();
    if (wave == 0) {
#pragma unroll
        for (int j = 0; j < 8; ++j)
            acc[j] += red[lane * 8 + j] + red[512 + lane * 8 + j] + red[1024 + lane * 8 + j];
        float inv = 1.f / fmaxf((float)(e - s), 1.f);
#pragma unroll
        for (int j = 0; j < 8; ++j) pooled[(size_t)g * 512 + lane * 8 + j] = acc[j] * inv;
    }
}

// ---------------- small MLP ----------------
__global__ __launch_bounds__(256) void k_mlp1(const float* __restrict__ pooled,
                                              const float* __restrict__ Wl1,
                                              const float* __restrict__ bl1,
                                              float* __restrict__ z) {
    __shared__ float sp[512];
    int i = blockIdx.x, j = threadIdx.x;
    sp[j]       = pooled[(size_t)i * 512 + j];
    sp[j + 256] = pooled[(size_t)i * 512 + 256 + j];
    __syncthreads();
    float acc = bl1[j];
#pragma unroll 4
    for (int k = 0; k < 512; ++k) acc = fmaf(sp[k], Wl1[(size_t)k * 256 + j], acc);
    z[(size_t)i * 256 + j] = fmaxf(acc, 0.f);
}

__global__ __launch_bounds__(128) void k_mlp2(const float* __restrict__ z,
                                              const float* __restrict__ Wl2,
                                              const float* __restrict__ bl2,
                                              float* __restrict__ out) {
    __shared__ float sz[256];
    int i = blockIdx.x, j = threadIdx.x;
    sz[j]       = z[(size_t)i * 256 + j];
    sz[j + 128] = z[(size_t)i * 256 + 128 + j];
    __syncthreads();
    float acc = bl2[j];
#pragma unroll 4
    for (int k = 0; k < 256; ++k) acc = fmaf(sz[k], Wl2[(size_t)k * 128 + j], acc);
    out[(size_t)i * 128 + j] = acc;
}

extern "C" void kernel_launch(void* const* d_in, const int* in_sizes, int n_in,
                              void* d_out, int out_size, void* d_ws, size_t ws_size,
                              hipStream_t stream) {
    const int*   x    = (const int*)d_in[0];
    const int*   ei   = (const int*)d_in[1];
    const int*   batch= (const int*)d_in[2];
    const float* emb  = (const float*)d_in[3];
    const float* W1   = (const float*)d_in[4];
    const float* b1   = (const float*)d_in[5];
    const float* g1   = (const float*)d_in[6];
    const float* be1  = (const float*)d_in[7];
    const float* W2   = (const float*)d_in[8];
    const float* b2   = (const float*)d_in[9];
    const float* g2   = (const float*)d_in[10];
    const float* be2  = (const float*)d_in[11];
    const float* Wl1  = (const float*)d_in[12];
    const float* bl1  = (const float*)d_in[13];
    const float* Wl2  = (const float*)d_in[14];
    const float* bl2  = (const float*)d_in[15];
    float* out = (float*)d_out;

    char* ws = (char*)d_ws;
    size_t o = 0;
    auto alloc = [&](size_t bytes) { char* p = ws + o; o += (bytes + 255) & ~(size_t)255; return p; };

    // ---- small persistent buffers (~8 MB) ----
    unsigned short* W1tb = (unsigned short*)alloc((size_t)512 * 256 * 2);
    unsigned short* W2tb = (unsigned short*)alloc((size_t)512 * 512 * 2);
    unsigned short* embB = (unsigned short*)alloc((size_t)1024 * 256 * 2);  // emb bf16 (1024-row pad)
    unsigned short* embW = (unsigned short*)alloc((size_t)1024 * 512 * 2);  // emb @ W1, bf16
    float* sums   = (float*)alloc(4 * 512 * 4);
    float* colsum1 = sums, *colsq1 = sums + 512, *colsum2 = sums + 1024, *colsq2 = sums + 1536;
    float* coeffs = (float*)alloc(4 * 512 * 4);
    float* a1 = coeffs, *c1 = coeffs + 512, *a2 = coeffs + 1024, *c2 = coeffs + 1536;
    int*   starts = (int*)alloc((N_GRAPHS + 1) * 4);
    float* pooled = (float*)alloc((size_t)N_GRAPHS * 512 * 4);
    float* zbuf   = (float*)alloc((size_t)N_GRAPHS * 256 * 4);
    int*   counts = (int*)alloc((size_t)N_NODES * 4);
    int*   rowptr = (int*)alloc((size_t)(N_NODES + 1) * 4);
    int*   cursor = (int*)alloc((size_t)N_NODES * 4);
    int*   srcs   = (int*)alloc((size_t)N_EDGES * 4);
    int*   bsum   = (int*)alloc((size_t)NBLK * 4);
    int*   bpre   = (int*)alloc((size_t)NBLK * 4);

    // ---- slotA (102.5 MB): agg2b(bf16, MPAD*512) ----
    unsigned short* agg2b = (unsigned short*)alloc((size_t)MPAD * 512 * 2);
    // ---- slotB (102.5 MB): pre1b -> pre2b (disjoint lifetimes) ----
    char* slotB = alloc((size_t)MPAD * 512 * 2);
    unsigned short* pre1b = (unsigned short*)slotB;
    unsigned short* pre2b = (unsigned short*)slotB;
    (void)ws_size; (void)in_sizes; (void)n_in; (void)out_size;

    // ---- CSR build (parallel 3-phase scan) ----
    k_zero_int<<<(N_NODES + 255) / 256, 256, 0, stream>>>(counts, N_NODES);
    k_zero_f<<<8, 256, 0, stream>>>(sums, 2048);
    k_hist<<<(N_EDGES + 255) / 256, 256, 0, stream>>>(ei, counts);
    k_blocksum<<<NBLK, SB, 0, stream>>>(counts, bsum);
    k_scan_bsum<<<1, 512, 0, stream>>>(bsum, bpre);
    k_scan_final<<<NBLK, SB, 0, stream>>>(counts, bpre, rowptr, cursor);
    k_fill<<<(N_EDGES + 255) / 256, 256, 0, stream>>>(ei, cursor, srcs);

    // ---- weight / table prep ----
    k_cvt_wt<<<(256 * 512 + 255) / 256, 256, 0, stream>>>(W1, W1tb, 256, 512);
    k_cvt_wt<<<(512 * 512 + 255) / 256, 256, 0, stream>>>(W2, W2tb, 512, 512);
    k_cvt_emb<<<1000, 256, 0, stream>>>(emb, embB);
    // embW = emb @ W1 (1024x512, rows >=1000 garbage but never gathered)
    k_gemm_bias_stats<256, false><<<32, 256, 0, stream>>>(
        embB, W1tb, nullptr, embW, nullptr, nullptr, 1024);

    // ---- layer 1 (gather-aggregate of embW rows; stats as streaming pass) ----
    k_gather_pre1<<<(N_NODES + 3) / 4, 256, 0, stream>>>(embW, x, rowptr, srcs, b1, pre1b);
    k_stats1<<<250, 256, 0, stream>>>(pre1b, colsum1, colsq1);
    k_bn_coeffs<<<2, 256, 0, stream>>>(colsum1, colsq1, g1, be1, a1, c1);

    // ---- layer 2 ----
    k_gather2<<<(N_NODES + 3) / 4, 256, 0, stream>>>(pre1b, rowptr, srcs, a1, c1, agg2b);
    k_gemm_bias_stats<512, true><<<GEMM_BLOCKS, 256, 0, stream>>>(
        agg2b, W2tb, b2, pre2b, colsum2, colsq2, N_NODES);
    k_bn_coeffs<<<2, 256, 0, stream>>>(colsum2, colsq2, g2, be2, a2, c2);

    // ---- pooling + MLP ----
    k_seg_starts<<<(N_NODES + 255) / 256, 256, 0, stream>>>(batch, starts);
    k_pool<<<N_GRAPHS, 256, 0, stream>>>(pre2b, starts, a2, c2, pooled);
    k_mlp1<<<N_GRAPHS, 256, 0, stream>>>(pooled, Wl1, bl1, zbuf);
    k_mlp2<<<N_GRAPHS, 128, 0, stream>>>(zbuf, Wl2, bl2, out);
}

// Round 9
// 449.904 us; speedup vs baseline: 1.3270x; 1.2448x over previous
//
#include <hip/hip_runtime.h>
#include <cstdint>
#include <cstddef>

#define N_NODES 100000
#define N_EDGES 250000
#define N_GRAPHS 512
#define MTILES 782            // ceil(100000/128)
#define MPAD (MTILES * 128)   // 100096
#define SB 256
#define NBLK ((N_NODES + SB - 1) / SB)   // 391
#define GEMM_BLOCKS 3136      // 98 groups * 32 (8 xcd * 4 n-tiles); m_tile = g*8+xcd in [0,784)
#define GP1_BLOCKS 2048       // grid-stride gather_pre1 blocks (8/CU, 32 waves/CU)

using f32x4  = __attribute__((ext_vector_type(4))) float;
using bf16x8 = __attribute__((ext_vector_type(8))) short;

struct alignas(8) U16x4 { unsigned short x, y, z, w; };

__device__ __forceinline__ unsigned short f32_to_bf16(float f) {
    union { float f; uint32_t u; } v; v.f = f;
    uint32_t r = v.u + 0x7FFF + ((v.u >> 16) & 1);   // RNE
    return (unsigned short)(r >> 16);
}
__device__ __forceinline__ float bf_lo(uint32_t u) {
    union { uint32_t u; float f; } v; v.u = u << 16; return v.f;
}
__device__ __forceinline__ float bf_hi(uint32_t u) {
    union { uint32_t u; float f; } v; v.u = u & 0xFFFF0000u; return v.f;
}

__device__ __forceinline__ void async_cp16(const void* g, void* l) {
    __builtin_amdgcn_global_load_lds(
        (const __attribute__((address_space(1))) void*)g,
        (__attribute__((address_space(3))) void*)l, 16, 0, 0);
}

// ---------------- utility zero kernels ----------------
__global__ void k_zero_int(int* __restrict__ p, int n) {
    int i = blockIdx.x * 256 + threadIdx.x;
    if (i < n) p[i] = 0;
}
__global__ void k_zero_f(float* __restrict__ p, int n) {
    int i = blockIdx.x * 256 + threadIdx.x;
    if (i < n) p[i] = 0.f;
}

// ---------------- CSR build ----------------
__global__ void k_hist(const int* __restrict__ ei, int* __restrict__ counts) {
    int e = blockIdx.x * 256 + threadIdx.x;
    if (e < N_EDGES) atomicAdd(&counts[ei[N_EDGES + e]], 1);
}

// --- 3-phase parallel exclusive scan of counts -> rowptr/cursor ---
__global__ __launch_bounds__(SB) void k_blocksum(const int* __restrict__ counts,
                                                 int* __restrict__ bsum) {
    __shared__ int red[4];
    int i = blockIdx.x * SB + threadIdx.x;
    int v = (i < N_NODES) ? counts[i] : 0;
#pragma unroll
    for (int off = 1; off < 64; off <<= 1) v += __shfl_xor(v, off);
    int wave = threadIdx.x >> 6, lane = threadIdx.x & 63;
    if (lane == 0) red[wave] = v;
    __syncthreads();
    if (threadIdx.x == 0) bsum[blockIdx.x] = red[0] + red[1] + red[2] + red[3];
}

__global__ __launch_bounds__(512) void k_scan_bsum(const int* __restrict__ bsum,
                                                   int* __restrict__ bpre) {
    __shared__ int s[512];
    int t = threadIdx.x;
    int orig = (t < NBLK) ? bsum[t] : 0;
    s[t] = orig;
    __syncthreads();
    for (int off = 1; off < 512; off <<= 1) {
        int v = (t >= off) ? s[t - off] : 0;
        __syncthreads();
        s[t] += v;
        __syncthreads();
    }
    if (t < NBLK) bpre[t] = s[t] - orig;   // exclusive prefix
}

__global__ __launch_bounds__(SB) void k_scan_final(const int* __restrict__ counts,
                                                   const int* __restrict__ bpre,
                                                   int* __restrict__ rowptr,
                                                   int* __restrict__ cursor) {
    __shared__ int s[SB];
    int t = threadIdx.x;
    int i = blockIdx.x * SB + t;
    int c = (i < N_NODES) ? counts[i] : 0;
    s[t] = c;
    __syncthreads();
    for (int off = 1; off < SB; off <<= 1) {
        int v = (t >= off) ? s[t - off] : 0;
        __syncthreads();
        s[t] += v;
        __syncthreads();
    }
    int pre = bpre[blockIdx.x] + s[t] - c;
    if (i < N_NODES) { rowptr[i] = pre; cursor[i] = pre; }
    if (i == 0) rowptr[N_NODES] = N_EDGES;
}

__global__ void k_fill(const int* __restrict__ ei, int* __restrict__ cursor,
                       int* __restrict__ srcs) {
    int e = blockIdx.x * 256 + threadIdx.x;
    if (e < N_EDGES) {
        int dst = ei[N_EDGES + e];
        int p = atomicAdd(&cursor[dst], 1);
        srcs[p] = ei[e];
    }
}

// ---- bf16 MFMA GEMM: Cb[M][512] = bf16(A @ Bt^T [+ bias]), optional fused col stats ----
// BK=64, XOR-swizzled LDS banks, XCD-aware block swizzle, LDS-slab coalesced epilogue.
#define SLAB_LD 136
template <int K, bool STATS>
__global__ __launch_bounds__(256) void k_gemm_bias_stats(
    const unsigned short* __restrict__ A, const unsigned short* __restrict__ Bt,
    const float* __restrict__ bias, unsigned short* __restrict__ Cb,
    float* __restrict__ colsum, float* __restrict__ colsq, int M) {
    __shared__ __align__(16) unsigned short sh[16384];   // lA[0:8192) lB[8192:16384); epilogue slab reuses [0:4352)
    unsigned short* lA = sh;
    unsigned short* lB = sh + 8192;
    const int tid  = threadIdx.x;
    const int wave = tid >> 6, lane = tid & 63;
    // XCD swizzle: 4 n-tiles of one m-tile share b%8 -> same XCD -> shared L2 for A
    const int b = blockIdx.x;
    const int m0 = ((b >> 5) * 8 + (b & 7)) * 128;
    const int n0 = ((b & 31) >> 3) * 128;
    if (m0 >= M) return;                       // padding-only m-tiles
    const int wr = (wave >> 1) * 64;
    const int wc = (wave & 1) * 64;
    const int quad = lane >> 4, m16 = lane & 15;

    f32x4 acc[4][4] = {};

    for (int k0 = 0; k0 < K; k0 += 64) {
        __syncthreads();
#pragma unroll
        for (int t = 0; t < 4; ++t) {
            int seg = (wave * 4 + t) * 64 + lane;   // 0..1023: row = seg>>3, lds col-slot = seg&7
            int row = seg >> 3, csl = seg & 7;
            int cs  = csl ^ (row & 7);              // XOR bank swizzle (global side)
            const unsigned short* gA = A + (size_t)(m0 + row) * K + (k0 + cs * 8);
            async_cp16(gA, &lA[seg * 8]);
            const unsigned short* gB = Bt + (size_t)(n0 + row) * K + (k0 + cs * 8);
            async_cp16(gB, &lB[seg * 8]);
        }
        __syncthreads();

#pragma unroll
        for (int h = 0; h < 2; ++h) {
            bf16x8 af[4], bfr[4];
#pragma unroll
            for (int rb = 0; rb < 4; ++rb) {
                int r = wr + rb * 16 + m16;
                int g = (h * 4 + quad) ^ (r & 7);
                af[rb] = *(const bf16x8*)&lA[r * 64 + g * 8];
            }
#pragma unroll
            for (int cb = 0; cb < 4; ++cb) {
                int r = wc + cb * 16 + m16;
                int g = (h * 4 + quad) ^ (r & 7);
                bfr[cb] = *(const bf16x8*)&lB[r * 64 + g * 8];
            }
#pragma unroll
            for (int rb = 0; rb < 4; ++rb)
#pragma unroll
                for (int cb = 0; cb < 4; ++cb)
                    acc[rb][cb] = __builtin_amdgcn_mfma_f32_16x16x32_bf16(
                        af[rb], bfr[cb], acc[rb][cb], 0, 0, 0);
        }
    }

    // ---- stats phase (registers + shuffles + atomics) ----
    float bvs[4];
#pragma unroll
    for (int cb = 0; cb < 4; ++cb) {
        int col = n0 + wc + cb * 16 + m16;
        float bv = STATS ? bias[col] : 0.f;
        bvs[cb] = bv;
        if constexpr (STATS) {
            float s = 0.f, s2 = 0.f;
#pragma unroll
            for (int rb = 0; rb < 4; ++rb) {
#pragma unroll
                for (int i = 0; i < 4; ++i) {
                    int row = m0 + wr + rb * 16 + quad * 4 + i;
                    if (row < M) {
                        float v = acc[rb][cb][i] + bv;
                        s += v; s2 += v * v;
                    }
                }
            }
            s  += __shfl_xor(s, 16);   s  += __shfl_xor(s, 32);
            s2 += __shfl_xor(s2, 16);  s2 += __shfl_xor(s2, 32);
            if (quad == 0) {
                atomicAdd(&colsum[col], s);
                atomicAdd(&colsq[col], s2);
            }
        }
    }

    // ---- store phase: per rb, 32x128 bf16 slab in LDS, then coalesced 16B stores ----
#pragma unroll
    for (int rb = 0; rb < 4; ++rb) {
        __syncthreads();   // protect prior K-chunk ds_reads (rb=0) / prior slab reads (rb>0)
#pragma unroll
        for (int cb = 0; cb < 4; ++cb) {
            int scol = wc + cb * 16 + m16;
#pragma unroll
            for (int i = 0; i < 4; ++i) {
                int sr = (wave >> 1) * 16 + quad * 4 + i;
                sh[sr * SLAB_LD + scol] = f32_to_bf16(acc[rb][cb][i] + bvs[cb]);
            }
        }
        __syncthreads();
#pragma unroll
        for (int s = 0; s < 2; ++s) {
            int u = tid + s * 256;            // 512 units of 16B: 32 rows x 16 col-chunks
            int sr = u >> 4, c8 = u & 15;
            int gr = m0 + (sr >> 4) * 64 + rb * 16 + (sr & 15);
            uint4 v = *(const uint4*)&sh[sr * SLAB_LD + c8 * 8];
            *(uint4*)&Cb[(size_t)gr * 512 + n0 + c8 * 8] = v;   // rows >= M land in padding
        }
    }
}

// ---------------- weights: W[K][N] fp32 -> Wt[N][K] bf16 ----------------
__global__ void k_cvt_wt(const float* __restrict__ W, unsigned short* __restrict__ Wt,
                         int K, int N) {
    int i = blockIdx.x * 256 + threadIdx.x;
    if (i < K * N) {
        int k = i / N, n = i - k * N;
        Wt[(size_t)n * K + k] = f32_to_bf16(W[i]);
    }
}

// ---------------- emb fp32 -> bf16 (row-major copy) ----------------
__global__ void k_cvt_emb(const float* __restrict__ e, unsigned short* __restrict__ o) {
    int i = blockIdx.x * 256 + threadIdx.x;
    if (i < 1000 * 256) o[i] = f32_to_bf16(e[i]);
}

// ---------------- BN coefficients: bn(x) = a*x + c ----------------
__global__ void k_bn_coeffs(const float* __restrict__ colsum, const float* __restrict__ colsq,
                            const float* __restrict__ g, const float* __restrict__ be,
                            float* __restrict__ a, float* __restrict__ c) {
    int f = blockIdx.x * 256 + threadIdx.x;
    if (f >= 512) return;
    float mu  = colsum[f] * (1.f / N_NODES);
    float var = colsq[f] * (1.f / N_NODES) - mu * mu;
    float ai  = g[f] * rsqrtf(var + 1e-5f);
    a[f] = ai;
    c[f] = be[f] - mu * ai;
}

// ---- layer 1 (factorized): pre1b[n] = bf16(b1 + sum over {n}+nbrs of embW[x[.]]) ----
// Grid-stride, 1 node/wave/step; fused column stats -> per-block partials (no 2nd pass).
__global__ __launch_bounds__(256) void k_gather_pre1(
    const unsigned short* __restrict__ embW, const int* __restrict__ x,
    const int* __restrict__ rowptr, const int* __restrict__ srcs,
    const float* __restrict__ b1, unsigned short* __restrict__ pre1b,
    float* __restrict__ part) {
    __shared__ float red[2][3][512];
    int wave = threadIdx.x >> 6, lane = threadIdx.x & 63;
    float4 bl = ((const float4*)b1)[lane * 2], bh = ((const float4*)b1)[lane * 2 + 1];
    float ssum[8] = {}, ssq[8] = {};
    for (int node = blockIdx.x * 4 + wave; node < N_NODES; node += GP1_BLOCKS * 4) {
        float acc[8] = { bl.x, bl.y, bl.z, bl.w, bh.x, bh.y, bh.z, bh.w };
        int j0 = rowptr[node], j1 = rowptr[node + 1];
        for (int j = j0 - 1; j < j1; ++j) {
            int s = (j < j0) ? node : srcs[j];      // first iteration: identity term
            int r = x[s];
            uint4 raw = ((const uint4*)(embW + (size_t)r * 512))[lane];
            acc[0] += bf_lo(raw.x); acc[1] += bf_hi(raw.x);
            acc[2] += bf_lo(raw.y); acc[3] += bf_hi(raw.y);
            acc[4] += bf_lo(raw.z); acc[5] += bf_hi(raw.z);
            acc[6] += bf_lo(raw.w); acc[7] += bf_hi(raw.w);
        }
        U16x4 o0{ f32_to_bf16(acc[0]), f32_to_bf16(acc[1]), f32_to_bf16(acc[2]), f32_to_bf16(acc[3]) };
        U16x4 o1{ f32_to_bf16(acc[4]), f32_to_bf16(acc[5]), f32_to_bf16(acc[6]), f32_to_bf16(acc[7]) };
        ((U16x4*)pre1b)[(size_t)node * 128 + lane * 2]     = o0;
        ((U16x4*)pre1b)[(size_t)node * 128 + lane * 2 + 1] = o1;
#pragma unroll
        for (int j2 = 0; j2 < 8; ++j2) { ssum[j2] += acc[j2]; ssq[j2] += acc[j2] * acc[j2]; }
    }
    if (wave != 0) {
#pragma unroll
        for (int j2 = 0; j2 < 8; ++j2) {
            red[0][wave - 1][lane * 8 + j2] = ssum[j2];
            red[1][wave - 1][lane * 8 + j2] = ssq[j2];
        }
    }
    __syncthreads();
    if (wave == 0) {
        float* p = part + (size_t)blockIdx.x * 1024;
#pragma unroll
        for (int j2 = 0; j2 < 8; ++j2) {
            int col = lane * 8 + j2;
            p[col]       = ssum[j2] + red[0][0][col] + red[0][1][col] + red[0][2][col];
            p[col + 512] = ssq[j2]  + red[1][0][col] + red[1][1][col] + red[1][2][col];
        }
    }
}

// ---- reduce GP1_BLOCKS x 1024 partials -> colsum1/colsq1 (32 blocks of 64 partials) ----
__global__ __launch_bounds__(256) void k_red_stats(const float* __restrict__ part,
                                                   float* __restrict__ colsum,
                                                   float* __restrict__ colsq) {
    int t = threadIdx.x;                     // each thread: 4 consecutive outputs (16B)
    float4 s = { 0.f, 0.f, 0.f, 0.f };
    int b0 = blockIdx.x * (GP1_BLOCKS / 32);
    for (int b = b0; b < b0 + GP1_BLOCKS / 32; ++b) {
        float4 v = ((const float4*)(part + (size_t)b * 1024))[t];
        s.x += v.x; s.y += v.y; s.z += v.z; s.w += v.w;
    }
    int o = t * 4;
    float* dst = (o < 512) ? (colsum + o) : (colsq + o - 512);
    atomicAdd(dst + 0, s.x); atomicAdd(dst + 1, s.y);
    atomicAdd(dst + 2, s.z); atomicAdd(dst + 3, s.w);
}

// ------- layer-2 aggregate (gather): agg2b[n] = bf16(f(pre1b[n]) + sum_j f(pre1b[src_j])) ----
__global__ __launch_bounds__(256) void k_gather2(
    const unsigned short* __restrict__ pre1b, const int* __restrict__ rowptr,
    const int* __restrict__ srcs, const float* __restrict__ a1,
    const float* __restrict__ c1, unsigned short* __restrict__ agg2b) {
    int wave = threadIdx.x >> 6, lane = threadIdx.x & 63;
    int node = blockIdx.x * 4 + wave;
    if (node >= N_NODES) return;
    float4 aa0 = ((const float4*)a1)[lane * 2], aa1 = ((const float4*)a1)[lane * 2 + 1];
    float4 cc0 = ((const float4*)c1)[lane * 2], cc1 = ((const float4*)c1)[lane * 2 + 1];
    float acc[8] = {};
    int j0 = rowptr[node], j1 = rowptr[node + 1];
    for (int j = j0 - 1; j < j1; ++j) {
        int s = (j < j0) ? node : srcs[j];          // first iteration: identity term
        uint4 raw = ((const uint4*)(pre1b + (size_t)s * 512))[lane];
        acc[0] += fmaxf(fmaf(aa0.x, bf_lo(raw.x), cc0.x), 0.f);
        acc[1] += fmaxf(fmaf(aa0.y, bf_hi(raw.x), cc0.y), 0.f);
        acc[2] += fmaxf(fmaf(aa0.z, bf_lo(raw.y), cc0.z), 0.f);
        acc[3] += fmaxf(fmaf(aa0.w, bf_hi(raw.y), cc0.w), 0.f);
        acc[4] += fmaxf(fmaf(aa1.x, bf_lo(raw.z), cc1.x), 0.f);
        acc[5] += fmaxf(fmaf(aa1.y, bf_hi(raw.z), cc1.y), 0.f);
        acc[6] += fmaxf(fmaf(aa1.z, bf_lo(raw.w), cc1.z), 0.f);
        acc[7] += fmaxf(fmaf(aa1.w, bf_hi(raw.w), cc1.w), 0.f);
    }
    U16x4 o0{ f32_to_bf16(acc[0]), f32_to_bf16(acc[1]), f32_to_bf16(acc[2]), f32_to_bf16(acc[3]) };
    U16x4 o1{ f32_to_bf16(acc[4]), f32_to_bf16(acc[5]), f32_to_bf16(acc[6]), f32_to_bf16(acc[7]) };
    ((U16x4*)agg2b)[(size_t)node * 128 + lane * 2]     = o0;
    ((U16x4*)agg2b)[(size_t)node * 128 + lane * 2 + 1] = o1;
}

// ---------------- graph segment starts from sorted batch ----------------
__global__ void k_seg_starts(const int* __restrict__ batch, int* __restrict__ starts) {
    int i = blockIdx.x * 256 + threadIdx.x;
    if (i >= N_NODES) return;
    int b = batch[i];
    if (i == 0) {
        for (int g = 0; g <= b; ++g) starts[g] = 0;
    } else {
        int p = batch[i - 1];
        for (int g = p + 1; g <= b; ++g) starts[g] = i;
    }
    if (i == N_NODES - 1) {
        for (int g = b + 1; g <= N_GRAPHS; ++g) starts[g] = N_NODES;
    }
}

// ------- pooling: pooled[g] = mean_n relu(a2*pre2b[n]+c2)  (pre2b bf16) -------
__global__ __launch_bounds__(256) void k_pool(const unsigned short* __restrict__ pre2b,
                                              const int* __restrict__ starts,
                                              const float* __restrict__ a2,
                                              const float* __restrict__ c2,
                                              float* __restrict__ pooled) {
    __shared__ float red[3 * 512];
    int g = blockIdx.x;
    int wave = threadIdx.x >> 6, lane = threadIdx.x & 63;
    int s = starts[g], e = starts[g + 1];
    float4 aa0 = ((const float4*)a2)[lane * 2], aa1 = ((const float4*)a2)[lane * 2 + 1];
    float4 cc0 = ((const float4*)c2)[lane * 2], cc1 = ((const float4*)c2)[lane * 2 + 1];
    float acc[8] = {};
    for (int n = s + wave; n < e; n += 4) {
        uint4 raw = ((const uint4*)(pre2b + (size_t)n * 512))[lane];
        acc[0] += fmaxf(fmaf(aa0.x, bf_lo(raw.x), cc0.x), 0.f);
        acc[1] += fmaxf(fmaf(aa0.y, bf_hi(raw.x), cc0.y), 0.f);
        acc[2] += fmaxf(fmaf(aa0.z, bf_lo(raw.y), cc0.z), 0.f);
        acc[3] += fmaxf(fmaf(aa0.w, bf_hi(raw.y), cc0.w), 0.f);
        acc[4] += fmaxf(fmaf(aa1.x, bf_lo(raw.z), cc1.x), 0.f);
        acc[5] += fmaxf(fmaf(aa1.y, bf_hi(raw.z), cc1.y), 0.f);
        acc[6] += fmaxf(fmaf(aa1.z, bf_lo(raw.w), cc1.z), 0.f);
        acc[7] += fmaxf(fmaf(aa1.w, bf_hi(raw.w), cc1.w), 0.f);
    }
    if (wave != 0) {
#pragma unroll
        for (int j = 0; j < 8; ++j) red[(wave - 1) * 512 + lane * 8 + j] = acc[j];
    }
    __syncthreads();
    if (wave == 0) {
#pragma unroll
        for (int j = 0; j < 8; ++j)
            acc[j] += red[lane * 8 + j] + red[512 + lane * 8 + j] + red[1024 + lane * 8 + j];
        float inv = 1.f / fmaxf((float)(e - s), 1.f);
#pragma unroll
        for (int j = 0; j < 8; ++j) pooled[(size_t)g * 512 + lane * 8 + j] = acc[j] * inv;
    }
}

// ---------------- small MLP ----------------
__global__ __launch_bounds__(256) void k_mlp1(const float* __restrict__ pooled,
                                              const float* __restrict__ Wl1,
                                              const float* __restrict__ bl1,
                                              float* __restrict__ z) {
    __shared__ float sp[512];
    int i = blockIdx.x, j = threadIdx.x;
    sp[j]       = pooled[(size_t)i * 512 + j];
    sp[j + 256] = pooled[(size_t)i * 512 + 256 + j];
    __syncthreads();
    float acc = bl1[j];
#pragma unroll 4
    for (int k = 0; k < 512; ++k) acc = fmaf(sp[k], Wl1[(size_t)k * 256 + j], acc);
    z[(size_t)i * 256 + j] = fmaxf(acc, 0.f);
}

__global__ __launch_bounds__(128) void k_mlp2(const float* __restrict__ z,
                                              const float* __restrict__ Wl2,
                                              const float* __restrict__ bl2,
                                              float* __restrict__ out) {
    __shared__ float sz[256];
    int i = blockIdx.x, j = threadIdx.x;
    sz[j]       = z[(size_t)i * 256 + j];
    sz[j + 128] = z[(size_t)i * 256 + 128 + j];
    __syncthreads();
    float acc = bl2[j];
#pragma unroll 4
    for (int k = 0; k < 256; ++k) acc = fmaf(sz[k], Wl2[(size_t)k * 128 + j], acc);
    out[(size_t)i * 128 + j] = acc;
}

extern "C" void kernel_launch(void* const* d_in, const int* in_sizes, int n_in,
                              void* d_out, int out_size, void* d_ws, size_t ws_size,
                              hipStream_t stream) {
    const int*   x    = (const int*)d_in[0];
    const int*   ei   = (const int*)d_in[1];
    const int*   batch= (const int*)d_in[2];
    const float* emb  = (const float*)d_in[3];
    const float* W1   = (const float*)d_in[4];
    const float* b1   = (const float*)d_in[5];
    const float* g1   = (const float*)d_in[6];
    const float* be1  = (const float*)d_in[7];
    const float* W2   = (const float*)d_in[8];
    const float* b2   = (const float*)d_in[9];
    const float* g2   = (const float*)d_in[10];
    const float* be2  = (const float*)d_in[11];
    const float* Wl1  = (const float*)d_in[12];
    const float* bl1  = (const float*)d_in[13];
    const float* Wl2  = (const float*)d_in[14];
    const float* bl2  = (const float*)d_in[15];
    float* out = (float*)d_out;

    char* ws = (char*)d_ws;
    size_t o = 0;
    auto alloc = [&](size_t bytes) { char* p = ws + o; o += (bytes + 255) & ~(size_t)255; return p; };

    // ---- small persistent buffers (~16 MB) ----
    unsigned short* W1tb = (unsigned short*)alloc((size_t)512 * 256 * 2);
    unsigned short* W2tb = (unsigned short*)alloc((size_t)512 * 512 * 2);
    unsigned short* embB = (unsigned short*)alloc((size_t)1024 * 256 * 2);  // emb bf16 (1024-row pad)
    unsigned short* embW = (unsigned short*)alloc((size_t)1024 * 512 * 2);  // emb @ W1, bf16
    float* sums   = (float*)alloc(4 * 512 * 4);
    float* colsum1 = sums, *colsq1 = sums + 512, *colsum2 = sums + 1024, *colsq2 = sums + 1536;
    float* coeffs = (float*)alloc(4 * 512 * 4);
    float* a1 = coeffs, *c1 = coeffs + 512, *a2 = coeffs + 1024, *c2 = coeffs + 1536;
    int*   starts = (int*)alloc((N_GRAPHS + 1) * 4);
    float* pooled = (float*)alloc((size_t)N_GRAPHS * 512 * 4);
    float* zbuf   = (float*)alloc((size_t)N_GRAPHS * 256 * 4);
    int*   counts = (int*)alloc((size_t)N_NODES * 4);
    int*   rowptr = (int*)alloc((size_t)(N_NODES + 1) * 4);
    int*   cursor = (int*)alloc((size_t)N_NODES * 4);
    int*   srcs   = (int*)alloc((size_t)N_EDGES * 4);
    int*   bsum   = (int*)alloc((size_t)NBLK * 4);
    int*   bpre   = (int*)alloc((size_t)NBLK * 4);
    float* part   = (float*)alloc((size_t)GP1_BLOCKS * 1024 * 4);           // 8 MB stats partials

    // ---- slotA (102.5 MB): agg2b(bf16, MPAD*512) ----
    unsigned short* agg2b = (unsigned short*)alloc((size_t)MPAD * 512 * 2);
    // ---- slotB (102.5 MB): pre1b -> pre2b (disjoint lifetimes) ----
    char* slotB = alloc((size_t)MPAD * 512 * 2);
    unsigned short* pre1b = (unsigned short*)slotB;
    unsigned short* pre2b = (unsigned short*)slotB;
    (void)ws_size; (void)in_sizes; (void)n_in; (void)out_size;

    // ---- CSR build (parallel 3-phase scan) ----
    k_zero_int<<<(N_NODES + 255) / 256, 256, 0, stream>>>(counts, N_NODES);
    k_zero_f<<<8, 256, 0, stream>>>(sums, 2048);
    k_hist<<<(N_EDGES + 255) / 256, 256, 0, stream>>>(ei, counts);
    k_blocksum<<<NBLK, SB, 0, stream>>>(counts, bsum);
    k_scan_bsum<<<1, 512, 0, stream>>>(bsum, bpre);
    k_scan_final<<<NBLK, SB, 0, stream>>>(counts, bpre, rowptr, cursor);
    k_fill<<<(N_EDGES + 255) / 256, 256, 0, stream>>>(ei, cursor, srcs);

    // ---- weight / table prep ----
    k_cvt_wt<<<(256 * 512 + 255) / 256, 256, 0, stream>>>(W1, W1tb, 256, 512);
    k_cvt_wt<<<(512 * 512 + 255) / 256, 256, 0, stream>>>(W2, W2tb, 512, 512);
    k_cvt_emb<<<1000, 256, 0, stream>>>(emb, embB);
    // embW = emb @ W1 (1024x512, rows >=1000 garbage but never gathered)
    k_gemm_bias_stats<256, false><<<32, 256, 0, stream>>>(
        embB, W1tb, nullptr, embW, nullptr, nullptr, 1024);

    // ---- layer 1 (gather-aggregate of embW rows; stats fused via partials) ----
    k_gather_pre1<<<GP1_BLOCKS, 256, 0, stream>>>(embW, x, rowptr, srcs, b1, pre1b, part);
    k_red_stats<<<32, 256, 0, stream>>>(part, colsum1, colsq1);
    k_bn_coeffs<<<2, 256, 0, stream>>>(colsum1, colsq1, g1, be1, a1, c1);

    // ---- layer 2 ----
    k_gather2<<<(N_NODES + 3) / 4, 256, 0, stream>>>(pre1b, rowptr, srcs, a1, c1, agg2b);
    k_gemm_bias_stats<512, true><<<GEMM_BLOCKS, 256, 0, stream>>>(
        agg2b, W2tb, b2, pre2b, colsum2, colsq2, N_NODES);
    k_bn_coeffs<<<2, 256, 0, stream>>>(colsum2, colsq2, g2, be2, a2, c2);

    // ---- pooling + MLP ----
    k_seg_starts<<<(N_NODES + 255) / 256, 256, 0, stream>>>(batch, starts);
    k_pool<<<N_GRAPHS, 256, 0, stream>>>(pre2b, starts, a2, c2, pooled);
    k_mlp1<<<N_GRAPHS, 256, 0, stream>>>(pooled, Wl1, bl1, zbuf);
    k_mlp2<<<N_GRAPHS, 128, 0, stream>>>(zbuf, Wl2, bl2, out);
}

// Round 10
// 445.581 us; speedup vs baseline: 1.3398x; 1.0097x over previous
//
#include <hip/hip_runtime.h>
#include <cstdint>
#include <cstddef>

#define N_NODES 100000
#define N_EDGES 250000
#define N_GRAPHS 512
#define MTILES 782            // ceil(100000/128)
#define MPAD (MTILES * 128)   // 100096
#define SB 256
#define NBLK ((N_NODES + SB - 1) / SB)   // 391
#define GEMM_BLOCKS 3136      // 98 groups * 32 (8 xcd * 4 n-tiles); m_tile = g*8+xcd in [0,784)
#define GP1_BLOCKS 2048       // grid-stride gather_pre1 blocks

using f32x4  = __attribute__((ext_vector_type(4))) float;
using bf16x8 = __attribute__((ext_vector_type(8))) short;

struct alignas(8) U16x4 { unsigned short x, y, z, w; };

__device__ __forceinline__ unsigned short f32_to_bf16(float f) {
    union { float f; uint32_t u; } v; v.f = f;
    uint32_t r = v.u + 0x7FFF + ((v.u >> 16) & 1);   // RNE
    return (unsigned short)(r >> 16);
}
__device__ __forceinline__ float bf_lo(uint32_t u) {
    union { uint32_t u; float f; } v; v.u = u << 16; return v.f;
}
__device__ __forceinline__ float bf_hi(uint32_t u) {
    union { uint32_t u; float f; } v; v.u = u & 0xFFFF0000u; return v.f;
}

__device__ __forceinline__ void async_cp16(const void* g, void* l) {
    __builtin_amdgcn_global_load_lds(
        (const __attribute__((address_space(1))) void*)g,
        (__attribute__((address_space(3))) void*)l, 16, 0, 0);
}

// ---------------- utility zero kernels ----------------
__global__ void k_zero_int(int* __restrict__ p, int n) {
    int i = blockIdx.x * 256 + threadIdx.x;
    if (i < n) p[i] = 0;
}
__global__ void k_zero_f(float* __restrict__ p, int n) {
    int i = blockIdx.x * 256 + threadIdx.x;
    if (i < n) p[i] = 0.f;
}

// ---------------- CSR build ----------------
__global__ void k_hist(const int* __restrict__ ei, int* __restrict__ counts) {
    int e = blockIdx.x * 256 + threadIdx.x;
    if (e < N_EDGES) atomicAdd(&counts[ei[N_EDGES + e]], 1);
}

// --- 3-phase parallel exclusive scan of counts -> rowptr/cursor ---
__global__ __launch_bounds__(SB) void k_blocksum(const int* __restrict__ counts,
                                                 int* __restrict__ bsum) {
    __shared__ int red[4];
    int i = blockIdx.x * SB + threadIdx.x;
    int v = (i < N_NODES) ? counts[i] : 0;
#pragma unroll
    for (int off = 1; off < 64; off <<= 1) v += __shfl_xor(v, off);
    int wave = threadIdx.x >> 6, lane = threadIdx.x & 63;
    if (lane == 0) red[wave] = v;
    __syncthreads();
    if (threadIdx.x == 0) bsum[blockIdx.x] = red[0] + red[1] + red[2] + red[3];
}

__global__ __launch_bounds__(512) void k_scan_bsum(const int* __restrict__ bsum,
                                                   int* __restrict__ bpre) {
    __shared__ int s[512];
    int t = threadIdx.x;
    int orig = (t < NBLK) ? bsum[t] : 0;
    s[t] = orig;
    __syncthreads();
    for (int off = 1; off < 512; off <<= 1) {
        int v = (t >= off) ? s[t - off] : 0;
        __syncthreads();
        s[t] += v;
        __syncthreads();
    }
    if (t < NBLK) bpre[t] = s[t] - orig;   // exclusive prefix
}

__global__ __launch_bounds__(SB) void k_scan_final(const int* __restrict__ counts,
                                                   const int* __restrict__ bpre,
                                                   int* __restrict__ rowptr,
                                                   int* __restrict__ cursor) {
    __shared__ int s[SB];
    int t = threadIdx.x;
    int i = blockIdx.x * SB + t;
    int c = (i < N_NODES) ? counts[i] : 0;
    s[t] = c;
    __syncthreads();
    for (int off = 1; off < SB; off <<= 1) {
        int v = (t >= off) ? s[t - off] : 0;
        __syncthreads();
        s[t] += v;
        __syncthreads();
    }
    int pre = bpre[blockIdx.x] + s[t] - c;
    if (i < N_NODES) { rowptr[i] = pre; cursor[i] = pre; }
    if (i == 0) rowptr[N_NODES] = N_EDGES;
}

// fill: also precompute xsrc[p] = x[src] (deletes a chain link in gather_pre1)
__global__ void k_fill(const int* __restrict__ ei, const int* __restrict__ x,
                       int* __restrict__ cursor, int* __restrict__ srcs,
                       int* __restrict__ xsrc) {
    int e = blockIdx.x * 256 + threadIdx.x;
    if (e < N_EDGES) {
        int src = ei[e];
        int dst = ei[N_EDGES + e];
        int p = atomicAdd(&cursor[dst], 1);
        srcs[p] = src;
        xsrc[p] = x[src];
    }
}

// ---- bf16 MFMA GEMM: Cb[M][512] = bf16(A @ Bt^T [+ bias]), optional fused col stats ----
// BK=64, XOR-swizzled LDS banks, XCD-aware block swizzle, LDS-slab coalesced epilogue.
#define SLAB_LD 136
template <int K, bool STATS>
__global__ __launch_bounds__(256) void k_gemm_bias_stats(
    const unsigned short* __restrict__ A, const unsigned short* __restrict__ Bt,
    const float* __restrict__ bias, unsigned short* __restrict__ Cb,
    float* __restrict__ colsum, float* __restrict__ colsq, int M) {
    __shared__ __align__(16) unsigned short sh[16384];   // lA[0:8192) lB[8192:16384); epilogue slab reuses [0:4352)
    unsigned short* lA = sh;
    unsigned short* lB = sh + 8192;
    const int tid  = threadIdx.x;
    const int wave = tid >> 6, lane = tid & 63;
    // XCD swizzle: 4 n-tiles of one m-tile share b%8 -> same XCD -> shared L2 for A
    const int b = blockIdx.x;
    const int m0 = ((b >> 5) * 8 + (b & 7)) * 128;
    const int n0 = ((b & 31) >> 3) * 128;
    if (m0 >= M) return;                       // padding-only m-tiles
    const int wr = (wave >> 1) * 64;
    const int wc = (wave & 1) * 64;
    const int quad = lane >> 4, m16 = lane & 15;

    f32x4 acc[4][4] = {};

    for (int k0 = 0; k0 < K; k0 += 64) {
        __syncthreads();
#pragma unroll
        for (int t = 0; t < 4; ++t) {
            int seg = (wave * 4 + t) * 64 + lane;   // 0..1023: row = seg>>3, lds col-slot = seg&7
            int row = seg >> 3, csl = seg & 7;
            int cs  = csl ^ (row & 7);              // XOR bank swizzle (global side)
            const unsigned short* gA = A + (size_t)(m0 + row) * K + (k0 + cs * 8);
            async_cp16(gA, &lA[seg * 8]);
            const unsigned short* gB = Bt + (size_t)(n0 + row) * K + (k0 + cs * 8);
            async_cp16(gB, &lB[seg * 8]);
        }
        __syncthreads();

#pragma unroll
        for (int h = 0; h < 2; ++h) {
            bf16x8 af[4], bfr[4];
#pragma unroll
            for (int rb = 0; rb < 4; ++rb) {
                int r = wr + rb * 16 + m16;
                int g = (h * 4 + quad) ^ (r & 7);
                af[rb] = *(const bf16x8*)&lA[r * 64 + g * 8];
            }
#pragma unroll
            for (int cb = 0; cb < 4; ++cb) {
                int r = wc + cb * 16 + m16;
                int g = (h * 4 + quad) ^ (r & 7);
                bfr[cb] = *(const bf16x8*)&lB[r * 64 + g * 8];
            }
#pragma unroll
            for (int rb = 0; rb < 4; ++rb)
#pragma unroll
                for (int cb = 0; cb < 4; ++cb)
                    acc[rb][cb] = __builtin_amdgcn_mfma_f32_16x16x32_bf16(
                        af[rb], bfr[cb], acc[rb][cb], 0, 0, 0);
        }
    }

    // ---- stats phase (registers + shuffles + atomics) ----
    float bvs[4];
#pragma unroll
    for (int cb = 0; cb < 4; ++cb) {
        int col = n0 + wc + cb * 16 + m16;
        float bv = STATS ? bias[col] : 0.f;
        bvs[cb] = bv;
        if constexpr (STATS) {
            float s = 0.f, s2 = 0.f;
#pragma unroll
            for (int rb = 0; rb < 4; ++rb) {
#pragma unroll
                for (int i = 0; i < 4; ++i) {
                    int row = m0 + wr + rb * 16 + quad * 4 + i;
                    if (row < M) {
                        float v = acc[rb][cb][i] + bv;
                        s += v; s2 += v * v;
                    }
                }
            }
            s  += __shfl_xor(s, 16);   s  += __shfl_xor(s, 32);
            s2 += __shfl_xor(s2, 16);  s2 += __shfl_xor(s2, 32);
            if (quad == 0) {
                atomicAdd(&colsum[col], s);
                atomicAdd(&colsq[col], s2);
            }
        }
    }

    // ---- store phase: per rb, 32x128 bf16 slab in LDS, then coalesced 16B stores ----
#pragma unroll
    for (int rb = 0; rb < 4; ++rb) {
        __syncthreads();   // protect prior K-chunk ds_reads (rb=0) / prior slab reads (rb>0)
#pragma unroll
        for (int cb = 0; cb < 4; ++cb) {
            int scol = wc + cb * 16 + m16;
#pragma unroll
            for (int i = 0; i < 4; ++i) {
                int sr = (wave >> 1) * 16 + quad * 4 + i;
                sh[sr * SLAB_LD + scol] = f32_to_bf16(acc[rb][cb][i] + bvs[cb]);
            }
        }
        __syncthreads();
#pragma unroll
        for (int s = 0; s < 2; ++s) {
            int u = tid + s * 256;            // 512 units of 16B: 32 rows x 16 col-chunks
            int sr = u >> 4, c8 = u & 15;
            int gr = m0 + (sr >> 4) * 64 + rb * 16 + (sr & 15);
            uint4 v = *(const uint4*)&sh[sr * SLAB_LD + c8 * 8];
            *(uint4*)&Cb[(size_t)gr * 512 + n0 + c8 * 8] = v;   // rows >= M land in padding
        }
    }
}

// ---------------- weights: W[K][N] fp32 -> Wt[N][K] bf16 ----------------
__global__ void k_cvt_wt(const float* __restrict__ W, unsigned short* __restrict__ Wt,
                         int K, int N) {
    int i = blockIdx.x * 256 + threadIdx.x;
    if (i < K * N) {
        int k = i / N, n = i - k * N;
        Wt[(size_t)n * K + k] = f32_to_bf16(W[i]);
    }
}

// ---------------- emb fp32 -> bf16 (row-major copy) ----------------
__global__ void k_cvt_emb(const float* __restrict__ e, unsigned short* __restrict__ o) {
    int i = blockIdx.x * 256 + threadIdx.x;
    if (i < 1000 * 256) o[i] = f32_to_bf16(e[i]);
}

// ---------------- BN coefficients: bn(x) = a*x + c ----------------
__global__ void k_bn_coeffs(const float* __restrict__ colsum, const float* __restrict__ colsq,
                            const float* __restrict__ g, const float* __restrict__ be,
                            float* __restrict__ a, float* __restrict__ c) {
    int f = blockIdx.x * 256 + threadIdx.x;
    if (f >= 512) return;
    float mu  = colsum[f] * (1.f / N_NODES);
    float var = colsq[f] * (1.f / N_NODES) - mu * mu;
    float ai  = g[f] * rsqrtf(var + 1e-5f);
    a[f] = ai;
    c[f] = be[f] - mu * ai;
}

// ---- layer 1 (factorized): pre1b[n] = bf16(b1 + sum over {n}+nbrs of embW[x[.]]) ----
// Grid-stride; software-pipelined index prefetch (xsrc precomputed in k_fill);
// fused column stats -> per-block partials.
__global__ __launch_bounds__(256) void k_gather_pre1(
    const unsigned short* __restrict__ embW, const int* __restrict__ x,
    const int* __restrict__ rowptr, const int* __restrict__ xsrc,
    const float* __restrict__ b1, unsigned short* __restrict__ pre1b,
    float* __restrict__ part) {
    __shared__ float red[2][3][512];
    int wave = threadIdx.x >> 6, lane = threadIdx.x & 63;
    float4 bl = ((const float4*)b1)[lane * 2], bh = ((const float4*)b1)[lane * 2 + 1];
    float ssum[8] = {}, ssq[8] = {};
    for (int node = blockIdx.x * 4 + wave; node < N_NODES; node += GP1_BLOCKS * 4) {
        float acc[8] = { bl.x, bl.y, bl.z, bl.w, bh.x, bh.y, bh.z, bh.w };
        int j0 = rowptr[node], j1 = rowptr[node + 1];
        int cnt = j1 - j0;                      // rows to sum: 1 (identity) + cnt
        int r_cur = x[node];                    // identity row index
        int r_nxt = (cnt > 0) ? xsrc[j0] : 0;   // prefetch first neighbor index
        for (int t = 0; t <= cnt; ++t) {
            uint4 raw = ((const uint4*)(embW + (size_t)r_cur * 512))[lane];   // issue row load
            int r_follow = (t + 1 < cnt) ? xsrc[j0 + t + 1] : 0;              // issue next index
            acc[0] += bf_lo(raw.x); acc[1] += bf_hi(raw.x);                   // waits on raw only
            acc[2] += bf_lo(raw.y); acc[3] += bf_hi(raw.y);
            acc[4] += bf_lo(raw.z); acc[5] += bf_hi(raw.z);
            acc[6] += bf_lo(raw.w); acc[7] += bf_hi(raw.w);
            r_cur = r_nxt; r_nxt = r_follow;
        }
        U16x4 o0{ f32_to_bf16(acc[0]), f32_to_bf16(acc[1]), f32_to_bf16(acc[2]), f32_to_bf16(acc[3]) };
        U16x4 o1{ f32_to_bf16(acc[4]), f32_to_bf16(acc[5]), f32_to_bf16(acc[6]), f32_to_bf16(acc[7]) };
        ((U16x4*)pre1b)[(size_t)node * 128 + lane * 2]     = o0;
        ((U16x4*)pre1b)[(size_t)node * 128 + lane * 2 + 1] = o1;
#pragma unroll
        for (int j2 = 0; j2 < 8; ++j2) { ssum[j2] += acc[j2]; ssq[j2] += acc[j2] * acc[j2]; }
    }
    if (wave != 0) {
#pragma unroll
        for (int j2 = 0; j2 < 8; ++j2) {
            red[0][wave - 1][lane * 8 + j2] = ssum[j2];
            red[1][wave - 1][lane * 8 + j2] = ssq[j2];
        }
    }
    __syncthreads();
    if (wave == 0) {
        float* p = part + (size_t)blockIdx.x * 1024;
#pragma unroll
        for (int j2 = 0; j2 < 8; ++j2) {
            int col = lane * 8 + j2;
            p[col]       = ssum[j2] + red[0][0][col] + red[0][1][col] + red[0][2][col];
            p[col + 512] = ssq[j2]  + red[1][0][col] + red[1][1][col] + red[1][2][col];
        }
    }
}

// ---- reduce GP1_BLOCKS x 1024 partials -> colsum1/colsq1 (32 blocks of 64 partials) ----
__global__ __launch_bounds__(256) void k_red_stats(const float* __restrict__ part,
                                                   float* __restrict__ colsum,
                                                   float* __restrict__ colsq) {
    int t = threadIdx.x;                     // each thread: 4 consecutive outputs (16B)
    float4 s = { 0.f, 0.f, 0.f, 0.f };
    int b0 = blockIdx.x * (GP1_BLOCKS / 32);
    for (int b = b0; b < b0 + GP1_BLOCKS / 32; ++b) {
        float4 v = ((const float4*)(part + (size_t)b * 1024))[t];
        s.x += v.x; s.y += v.y; s.z += v.z; s.w += v.w;
    }
    int o = t * 4;
    float* dst = (o < 512) ? (colsum + o) : (colsq + o - 512);
    atomicAdd(dst + 0, s.x); atomicAdd(dst + 1, s.y);
    atomicAdd(dst + 2, s.z); atomicAdd(dst + 3, s.w);
}

// ------- layer-2 aggregate (gather): agg2b[n] = bf16(f(pre1b[n]) + sum_j f(pre1b[src_j])) ----
// Software-pipelined: next src index issued before current row's accumulate.
__global__ __launch_bounds__(256) void k_gather2(
    const unsigned short* __restrict__ pre1b, const int* __restrict__ rowptr,
    const int* __restrict__ srcs, const float* __restrict__ a1,
    const float* __restrict__ c1, unsigned short* __restrict__ agg2b) {
    int wave = threadIdx.x >> 6, lane = threadIdx.x & 63;
    int node = blockIdx.x * 4 + wave;
    if (node >= N_NODES) return;
    float4 aa0 = ((const float4*)a1)[lane * 2], aa1 = ((const float4*)a1)[lane * 2 + 1];
    float4 cc0 = ((const float4*)c1)[lane * 2], cc1 = ((const float4*)c1)[lane * 2 + 1];
    float acc[8] = {};
    int j0 = rowptr[node], j1 = rowptr[node + 1];
    int cnt = j1 - j0;
    int s_cur = node;                           // identity row first
    int s_nxt = (cnt > 0) ? srcs[j0] : 0;
    for (int t = 0; t <= cnt; ++t) {
        uint4 raw = ((const uint4*)(pre1b + (size_t)s_cur * 512))[lane];   // issue row load
        int s_follow = (t + 1 < cnt) ? srcs[j0 + t + 1] : 0;               // issue next index
        acc[0] += fmaxf(fmaf(aa0.x, bf_lo(raw.x), cc0.x), 0.f);
        acc[1] += fmaxf(fmaf(aa0.y, bf_hi(raw.x), cc0.y), 0.f);
        acc[2] += fmaxf(fmaf(aa0.z, bf_lo(raw.y), cc0.z), 0.f);
        acc[3] += fmaxf(fmaf(aa0.w, bf_hi(raw.y), cc0.w), 0.f);
        acc[4] += fmaxf(fmaf(aa1.x, bf_lo(raw.z), cc1.x), 0.f);
        acc[5] += fmaxf(fmaf(aa1.y, bf_hi(raw.z), cc1.y), 0.f);
        acc[6] += fmaxf(fmaf(aa1.z, bf_lo(raw.w), cc1.z), 0.f);
        acc[7] += fmaxf(fmaf(aa1.w, bf_hi(raw.w), cc1.w), 0.f);
        s_cur = s_nxt; s_nxt = s_follow;
    }
    U16x4 o0{ f32_to_bf16(acc[0]), f32_to_bf16(acc[1]), f32_to_bf16(acc[2]), f32_to_bf16(acc[3]) };
    U16x4 o1{ f32_to_bf16(acc[4]), f32_to_bf16(acc[5]), f32_to_bf16(acc[6]), f32_to_bf16(acc[7]) };
    ((U16x4*)agg2b)[(size_t)node * 128 + lane * 2]     = o0;
    ((U16x4*)agg2b)[(size_t)node * 128 + lane * 2 + 1] = o1;
}

// ---------------- graph segment starts from sorted batch ----------------
__global__ void k_seg_starts(const int* __restrict__ batch, int* __restrict__ starts) {
    int i = blockIdx.x * 256 + threadIdx.x;
    if (i >= N_NODES) return;
    int b = batch[i];
    if (i == 0) {
        for (int g = 0; g <= b; ++g) starts[g] = 0;
    } else {
        int p = batch[i - 1];
        for (int g = p + 1; g <= b; ++g) starts[g] = i;
    }
    if (i == N_NODES - 1) {
        for (int g = b + 1; g <= N_GRAPHS; ++g) starts[g] = N_NODES;
    }
}

// ------- pooling: pooled[g] = mean_n relu(a2*pre2b[n]+c2)  (pre2b bf16) -------
__global__ __launch_bounds__(256) void k_pool(const unsigned short* __restrict__ pre2b,
                                              const int* __restrict__ starts,
                                              const float* __restrict__ a2,
                                              const float* __restrict__ c2,
                                              float* __restrict__ pooled) {
    __shared__ float red[3 * 512];
    int g = blockIdx.x;
    int wave = threadIdx.x >> 6, lane = threadIdx.x & 63;
    int s = starts[g], e = starts[g + 1];
    float4 aa0 = ((const float4*)a2)[lane * 2], aa1 = ((const float4*)a2)[lane * 2 + 1];
    float4 cc0 = ((const float4*)c2)[lane * 2], cc1 = ((const float4*)c2)[lane * 2 + 1];
    float acc[8] = {};
    for (int n = s + wave; n < e; n += 4) {
        uint4 raw = ((const uint4*)(pre2b + (size_t)n * 512))[lane];
        acc[0] += fmaxf(fmaf(aa0.x, bf_lo(raw.x), cc0.x), 0.f);
        acc[1] += fmaxf(fmaf(aa0.y, bf_hi(raw.x), cc0.y), 0.f);
        acc[2] += fmaxf(fmaf(aa0.z, bf_lo(raw.y), cc0.z), 0.f);
        acc[3] += fmaxf(fmaf(aa0.w, bf_hi(raw.y), cc0.w), 0.f);
        acc[4] += fmaxf(fmaf(aa1.x, bf_lo(raw.z), cc1.x), 0.f);
        acc[5] += fmaxf(fmaf(aa1.y, bf_hi(raw.z), cc1.y), 0.f);
        acc[6] += fmaxf(fmaf(aa1.z, bf_lo(raw.w), cc1.z), 0.f);
        acc[7] += fmaxf(fmaf(aa1.w, bf_hi(raw.w), cc1.w), 0.f);
    }
    if (wave != 0) {
#pragma unroll
        for (int j = 0; j < 8; ++j) red[(wave - 1) * 512 + lane * 8 + j] = acc[j];
    }
    __syncthreads();
    if (wave == 0) {
#pragma unroll
        for (int j = 0; j < 8; ++j)
            acc[j] += red[lane * 8 + j] + red[512 + lane * 8 + j] + red[1024 + lane * 8 + j];
        float inv = 1.f / fmaxf((float)(e - s), 1.f);
#pragma unroll
        for (int j = 0; j < 8; ++j) pooled[(size_t)g * 512 + lane * 8 + j] = acc[j] * inv;
    }
}

// ---------------- small MLP ----------------
__global__ __launch_bounds__(256) void k_mlp1(const float* __restrict__ pooled,
                                              const float* __restrict__ Wl1,
                                              const float* __restrict__ bl1,
                                              float* __restrict__ z) {
    __shared__ float sp[512];
    int i = blockIdx.x, j = threadIdx.x;
    sp[j]       = pooled[(size_t)i * 512 + j];
    sp[j + 256] = pooled[(size_t)i * 512 + 256 + j];
    __syncthreads();
    float acc = bl1[j];
#pragma unroll 4
    for (int k = 0; k < 512; ++k) acc = fmaf(sp[k], Wl1[(size_t)k * 256 + j], acc);
    z[(size_t)i * 256 + j] = fmaxf(acc, 0.f);
}

__global__ __launch_bounds__(128) void k_mlp2(const float* __restrict__ z,
                                              const float* __restrict__ Wl2,
                                              const float* __restrict__ bl2,
                                              float* __restrict__ out) {
    __shared__ float sz[256];
    int i = blockIdx.x, j = threadIdx.x;
    sz[j]       = z[(size_t)i * 256 + j];
    sz[j + 128] = z[(size_t)i * 256 + 128 + j];
    __syncthreads();
    float acc = bl2[j];
#pragma unroll 4
    for (int k = 0; k < 256; ++k) acc = fmaf(sz[k], Wl2[(size_t)k * 128 + j], acc);
    out[(size_t)i * 128 + j] = acc;
}

extern "C" void kernel_launch(void* const* d_in, const int* in_sizes, int n_in,
                              void* d_out, int out_size, void* d_ws, size_t ws_size,
                              hipStream_t stream) {
    const int*   x    = (const int*)d_in[0];
    const int*   ei   = (const int*)d_in[1];
    const int*   batch= (const int*)d_in[2];
    const float* emb  = (const float*)d_in[3];
    const float* W1   = (const float*)d_in[4];
    const float* b1   = (const float*)d_in[5];
    const float* g1   = (const float*)d_in[6];
    const float* be1  = (const float*)d_in[7];
    const float* W2   = (const float*)d_in[8];
    const float* b2   = (const float*)d_in[9];
    const float* g2   = (const float*)d_in[10];
    const float* be2  = (const float*)d_in[11];
    const float* Wl1  = (const float*)d_in[12];
    const float* bl1  = (const float*)d_in[13];
    const float* Wl2  = (const float*)d_in[14];
    const float* bl2  = (const float*)d_in[15];
    float* out = (float*)d_out;

    char* ws = (char*)d_ws;
    size_t o = 0;
    auto alloc = [&](size_t bytes) { char* p = ws + o; o += (bytes + 255) & ~(size_t)255; return p; };

    // ---- small persistent buffers (~17 MB) ----
    unsigned short* W1tb = (unsigned short*)alloc((size_t)512 * 256 * 2);
    unsigned short* W2tb = (unsigned short*)alloc((size_t)512 * 512 * 2);
    unsigned short* embB = (unsigned short*)alloc((size_t)1024 * 256 * 2);  // emb bf16 (1024-row pad)
    unsigned short* embW = (unsigned short*)alloc((size_t)1024 * 512 * 2);  // emb @ W1, bf16
    float* sums   = (float*)alloc(4 * 512 * 4);
    float* colsum1 = sums, *colsq1 = sums + 512, *colsum2 = sums + 1024, *colsq2 = sums + 1536;
    float* coeffs = (float*)alloc(4 * 512 * 4);
    float* a1 = coeffs, *c1 = coeffs + 512, *a2 = coeffs + 1024, *c2 = coeffs + 1536;
    int*   starts = (int*)alloc((N_GRAPHS + 1) * 4);
    float* pooled = (float*)alloc((size_t)N_GRAPHS * 512 * 4);
    float* zbuf   = (float*)alloc((size_t)N_GRAPHS * 256 * 4);
    int*   counts = (int*)alloc((size_t)N_NODES * 4);
    int*   rowptr = (int*)alloc((size_t)(N_NODES + 1) * 4);
    int*   cursor = (int*)alloc((size_t)N_NODES * 4);
    int*   srcs   = (int*)alloc((size_t)N_EDGES * 4);
    int*   xsrc   = (int*)alloc((size_t)N_EDGES * 4);
    int*   bsum   = (int*)alloc((size_t)NBLK * 4);
    int*   bpre   = (int*)alloc((size_t)NBLK * 4);
    float* part   = (float*)alloc((size_t)GP1_BLOCKS * 1024 * 4);           // 8 MB stats partials

    // ---- slotA (102.5 MB): agg2b(bf16, MPAD*512) ----
    unsigned short* agg2b = (unsigned short*)alloc((size_t)MPAD * 512 * 2);
    // ---- slotB (102.5 MB): pre1b -> pre2b (disjoint lifetimes) ----
    char* slotB = alloc((size_t)MPAD * 512 * 2);
    unsigned short* pre1b = (unsigned short*)slotB;
    unsigned short* pre2b = (unsigned short*)slotB;
    (void)ws_size; (void)in_sizes; (void)n_in; (void)out_size;

    // ---- CSR build (parallel 3-phase scan) ----
    k_zero_int<<<(N_NODES + 255) / 256, 256, 0, stream>>>(counts, N_NODES);
    k_zero_f<<<8, 256, 0, stream>>>(sums, 2048);
    k_hist<<<(N_EDGES + 255) / 256, 256, 0, stream>>>(ei, counts);
    k_blocksum<<<NBLK, SB, 0, stream>>>(counts, bsum);
    k_scan_bsum<<<1, 512, 0, stream>>>(bsum, bpre);
    k_scan_final<<<NBLK, SB, 0, stream>>>(counts, bpre, rowptr, cursor);
    k_fill<<<(N_EDGES + 255) / 256, 256, 0, stream>>>(ei, x, cursor, srcs, xsrc);

    // ---- weight / table prep ----
    k_cvt_wt<<<(256 * 512 + 255) / 256, 256, 0, stream>>>(W1, W1tb, 256, 512);
    k_cvt_wt<<<(512 * 512 + 255) / 256, 256, 0, stream>>>(W2, W2tb, 512, 512);
    k_cvt_emb<<<1000, 256, 0, stream>>>(emb, embB);
    // embW = emb @ W1 (1024x512, rows >=1000 garbage but never gathered)
    k_gemm_bias_stats<256, false><<<32, 256, 0, stream>>>(
        embB, W1tb, nullptr, embW, nullptr, nullptr, 1024);

    // ---- layer 1 (gather-aggregate of embW rows; stats fused via partials) ----
    k_gather_pre1<<<GP1_BLOCKS, 256, 0, stream>>>(embW, x, rowptr, xsrc, b1, pre1b, part);
    k_red_stats<<<32, 256, 0, stream>>>(part, colsum1, colsq1);
    k_bn_coeffs<<<2, 256, 0, stream>>>(colsum1, colsq1, g1, be1, a1, c1);

    // ---- layer 2 ----
    k_gather2<<<(N_NODES + 3) / 4, 256, 0, stream>>>(pre1b, rowptr, srcs, a1, c1, agg2b);
    k_gemm_bias_stats<512, true><<<GEMM_BLOCKS, 256, 0, stream>>>(
        agg2b, W2tb, b2, pre2b, colsum2, colsq2, N_NODES);
    k_bn_coeffs<<<2, 256, 0, stream>>>(colsum2, colsq2, g2, be2, a2, c2);

    // ---- pooling + MLP ----
    k_seg_starts<<<(N_NODES + 255) / 256, 256, 0, stream>>>(batch, starts);
    k_pool<<<N_GRAPHS, 256, 0, stream>>>(pre2b, starts, a2, c2, pooled);
    k_mlp1<<<N_GRAPHS, 256, 0, stream>>>(pooled, Wl1, bl1, zbuf);
    k_mlp2<<<N_GRAPHS, 128, 0, stream>>>(zbuf, Wl2, bl2, out);
}

// Round 11
// 418.979 us; speedup vs baseline: 1.4249x; 1.0635x over previous
//
#include <hip/hip_runtime.h>
#include <cstdint>
#include <cstddef>

#define N_NODES 100000
#define N_EDGES 250000
#define N_GRAPHS 512
#define MTILES 782            // ceil(100000/128)
#define MPAD (MTILES * 128)   // 100096
#define SB 256
#define NBLK ((N_NODES + SB - 1) / SB)   // 391
#define GEMM_BLOCKS 3136      // 98 groups * 32 (8 xcd * 4 n-tiles); m_tile = g*8+xcd in [0,784)
#define GP1_BLOCKS 2048       // grid-stride gather_pre1 blocks

using f32x4  = __attribute__((ext_vector_type(4))) float;
using bf16x8 = __attribute__((ext_vector_type(8))) short;

struct alignas(8) U16x4 { unsigned short x, y, z, w; };

__device__ __forceinline__ unsigned short f32_to_bf16(float f) {
    union { float f; uint32_t u; } v; v.f = f;
    uint32_t r = v.u + 0x7FFF + ((v.u >> 16) & 1);   // RNE
    return (unsigned short)(r >> 16);
}
__device__ __forceinline__ float bf_lo(uint32_t u) {
    union { uint32_t u; float f; } v; v.u = u << 16; return v.f;
}
__device__ __forceinline__ float bf_hi(uint32_t u) {
    union { uint32_t u; float f; } v; v.u = u & 0xFFFF0000u; return v.f;
}

__device__ __forceinline__ void async_cp16(const void* g, void* l) {
    __builtin_amdgcn_global_load_lds(
        (const __attribute__((address_space(1))) void*)g,
        (__attribute__((address_space(3))) void*)l, 16, 0, 0);
}

// ---------------- utility zero kernels ----------------
__global__ void k_zero_int(int* __restrict__ p, int n) {
    int i = blockIdx.x * 256 + threadIdx.x;
    if (i < n) p[i] = 0;
}
__global__ void k_zero_f(float* __restrict__ p, int n) {
    int i = blockIdx.x * 256 + threadIdx.x;
    if (i < n) p[i] = 0.f;
}

// ---------------- CSR build ----------------
__global__ void k_hist(const int* __restrict__ ei, int* __restrict__ counts) {
    int e = blockIdx.x * 256 + threadIdx.x;
    if (e < N_EDGES) atomicAdd(&counts[ei[N_EDGES + e]], 1);
}

// --- 3-phase parallel exclusive scan of counts -> rowptr/cursor ---
__global__ __launch_bounds__(SB) void k_blocksum(const int* __restrict__ counts,
                                                 int* __restrict__ bsum) {
    __shared__ int red[4];
    int i = blockIdx.x * SB + threadIdx.x;
    int v = (i < N_NODES) ? counts[i] : 0;
#pragma unroll
    for (int off = 1; off < 64; off <<= 1) v += __shfl_xor(v, off);
    int wave = threadIdx.x >> 6, lane = threadIdx.x & 63;
    if (lane == 0) red[wave] = v;
    __syncthreads();
    if (threadIdx.x == 0) bsum[blockIdx.x] = red[0] + red[1] + red[2] + red[3];
}

__global__ __launch_bounds__(512) void k_scan_bsum(const int* __restrict__ bsum,
                                                   int* __restrict__ bpre) {
    __shared__ int s[512];
    int t = threadIdx.x;
    int orig = (t < NBLK) ? bsum[t] : 0;
    s[t] = orig;
    __syncthreads();
    for (int off = 1; off < 512; off <<= 1) {
        int v = (t >= off) ? s[t - off] : 0;
        __syncthreads();
        s[t] += v;
        __syncthreads();
    }
    if (t < NBLK) bpre[t] = s[t] - orig;   // exclusive prefix
}

__global__ __launch_bounds__(SB) void k_scan_final(const int* __restrict__ counts,
                                                   const int* __restrict__ bpre,
                                                   int* __restrict__ rowptr,
                                                   int* __restrict__ cursor) {
    __shared__ int s[SB];
    int t = threadIdx.x;
    int i = blockIdx.x * SB + t;
    int c = (i < N_NODES) ? counts[i] : 0;
    s[t] = c;
    __syncthreads();
    for (int off = 1; off < SB; off <<= 1) {
        int v = (t >= off) ? s[t - off] : 0;
        __syncthreads();
        s[t] += v;
        __syncthreads();
    }
    int pre = bpre[blockIdx.x] + s[t] - c;
    if (i < N_NODES) { rowptr[i] = pre; cursor[i] = pre; }
    if (i == 0) rowptr[N_NODES] = N_EDGES;
}

// fill: also precompute xsrc[p] = x[src]
__global__ void k_fill(const int* __restrict__ ei, const int* __restrict__ x,
                       int* __restrict__ cursor, int* __restrict__ srcs,
                       int* __restrict__ xsrc) {
    int e = blockIdx.x * 256 + threadIdx.x;
    if (e < N_EDGES) {
        int src = ei[e];
        int dst = ei[N_EDGES + e];
        int p = atomicAdd(&cursor[dst], 1);
        srcs[p] = src;
        xsrc[p] = x[src];
    }
}

// ---- bf16 MFMA GEMM: Cb[M][512] = bf16(A @ Bt^T [+ bias]) ----
// BK=64, XOR-swizzled LDS banks, XCD-aware block swizzle, LDS-slab coalesced epilogue.
// STATS: column sums/sqs -> per-block partials gpart[b*256] (NO global atomics).
#define SLAB_LD 136
template <int K, bool STATS>
__global__ __launch_bounds__(256) void k_gemm_bias_stats(
    const unsigned short* __restrict__ A, const unsigned short* __restrict__ Bt,
    const float* __restrict__ bias, unsigned short* __restrict__ Cb,
    float* __restrict__ gpart, int M) {
    __shared__ __align__(16) unsigned short sh[16384];   // lA[0:8192) lB[8192:16384); reused as slab/fred
    unsigned short* lA = sh;
    unsigned short* lB = sh + 8192;
    const int tid  = threadIdx.x;
    const int wave = tid >> 6, lane = tid & 63;
    const int b = blockIdx.x;
    const int m0 = ((b >> 5) * 8 + (b & 7)) * 128;
    const int n0 = ((b & 31) >> 3) * 128;
    if (m0 >= M) {                              // padding-only m-tiles: zero partial slot
        if constexpr (STATS) gpart[(size_t)b * 256 + tid] = 0.f;
        return;
    }
    const int wr = (wave >> 1) * 64;
    const int wc = (wave & 1) * 64;
    const int quad = lane >> 4, m16 = lane & 15;

    f32x4 acc[4][4] = {};

    for (int k0 = 0; k0 < K; k0 += 64) {
        __syncthreads();
#pragma unroll
        for (int t = 0; t < 4; ++t) {
            int seg = (wave * 4 + t) * 64 + lane;   // 0..1023: row = seg>>3, lds col-slot = seg&7
            int row = seg >> 3, csl = seg & 7;
            int cs  = csl ^ (row & 7);              // XOR bank swizzle (global side)
            const unsigned short* gA = A + (size_t)(m0 + row) * K + (k0 + cs * 8);
            async_cp16(gA, &lA[seg * 8]);
            const unsigned short* gB = Bt + (size_t)(n0 + row) * K + (k0 + cs * 8);
            async_cp16(gB, &lB[seg * 8]);
        }
        __syncthreads();

#pragma unroll
        for (int h = 0; h < 2; ++h) {
            bf16x8 af[4], bfr[4];
#pragma unroll
            for (int rb = 0; rb < 4; ++rb) {
                int r = wr + rb * 16 + m16;
                int g = (h * 4 + quad) ^ (r & 7);
                af[rb] = *(const bf16x8*)&lA[r * 64 + g * 8];
            }
#pragma unroll
            for (int cb = 0; cb < 4; ++cb) {
                int r = wc + cb * 16 + m16;
                int g = (h * 4 + quad) ^ (r & 7);
                bfr[cb] = *(const bf16x8*)&lB[r * 64 + g * 8];
            }
#pragma unroll
            for (int rb = 0; rb < 4; ++rb)
#pragma unroll
                for (int cb = 0; cb < 4; ++cb)
                    acc[rb][cb] = __builtin_amdgcn_mfma_f32_16x16x32_bf16(
                        af[rb], bfr[cb], acc[rb][cb], 0, 0, 0);
        }
    }

    // ---- bias + stats phase (shuffle reduce -> LDS -> per-block partial; no atomics) ----
    float bvs[4];
    float sArr[4], qArr[4];
#pragma unroll
    for (int cb = 0; cb < 4; ++cb) {
        int col = n0 + wc + cb * 16 + m16;
        float bv = STATS ? bias[col] : 0.f;
        bvs[cb] = bv;
        if constexpr (STATS) {
            float s = 0.f, s2 = 0.f;
#pragma unroll
            for (int rb = 0; rb < 4; ++rb) {
#pragma unroll
                for (int i = 0; i < 4; ++i) {
                    int row = m0 + wr + rb * 16 + quad * 4 + i;
                    if (row < M) {
                        float v = acc[rb][cb][i] + bv;
                        s += v; s2 += v * v;
                    }
                }
            }
            s  += __shfl_xor(s, 16);   s  += __shfl_xor(s, 32);
            s2 += __shfl_xor(s2, 16);  s2 += __shfl_xor(s2, 32);
            sArr[cb] = s; qArr[cb] = s2;
        }
    }
    if constexpr (STATS) {
        __syncthreads();                         // all waves done with lA/lB ds_reads
        float* fred = (float*)sh;                // fred[0:256)=sums(2 pairs x 128), [256:512)=sqs
        if (quad == 0) {
            int pair = wave >> 1;                // waves {0,2}->cols 0-63? no: wave0/2 share wc
#pragma unroll
            for (int cb = 0; cb < 4; ++cb) {
                int lc = wc + cb * 16 + m16;     // local col in [0,128)
                fred[pair * 128 + lc]       = sArr[cb];
                fred[256 + pair * 128 + lc] = qArr[cb];
            }
        }
        __syncthreads();
        if (tid < 128) {
            gpart[(size_t)b * 256 + tid]       = fred[tid] + fred[128 + tid];
            gpart[(size_t)b * 256 + 128 + tid] = fred[256 + tid] + fred[384 + tid];
        }
    }

    // ---- store phase: per rb, 32x128 bf16 slab in LDS, then coalesced 16B stores ----
#pragma unroll
    for (int rb = 0; rb < 4; ++rb) {
        __syncthreads();   // protect prior fred/slab reads before overwrite
#pragma unroll
        for (int cb = 0; cb < 4; ++cb) {
            int scol = wc + cb * 16 + m16;
#pragma unroll
            for (int i = 0; i < 4; ++i) {
                int sr = (wave >> 1) * 16 + quad * 4 + i;
                sh[sr * SLAB_LD + scol] = f32_to_bf16(acc[rb][cb][i] + bvs[cb]);
            }
        }
        __syncthreads();
#pragma unroll
        for (int s = 0; s < 2; ++s) {
            int u = tid + s * 256;            // 512 units of 16B: 32 rows x 16 col-chunks
            int sr = u >> 4, c8 = u & 15;
            int gr = m0 + (sr >> 4) * 64 + rb * 16 + (sr & 15);
            uint4 v = *(const uint4*)&sh[sr * SLAB_LD + c8 * 8];
            *(uint4*)&Cb[(size_t)gr * 512 + n0 + c8 * 8] = v;   // rows >= M land in padding
        }
    }
}

// ---- reduce GEMM partials: 32 blocks (4 n_tiles x 8 slices), coalesced ----
__global__ __launch_bounds__(256) void k_red_gemm(const float* __restrict__ gpart,
                                                  float* __restrict__ colsum,
                                                  float* __restrict__ colsq) {
    int r = blockIdx.x, t = threadIdx.x;
    int n_tile = r >> 3, slice = r & 7;
    int g0 = slice * 13, g1 = min(g0 + 13, 98);
    float acc = 0.f;
    for (int g = g0; g < g1; ++g) {
#pragma unroll
        for (int xcd = 0; xcd < 8; ++xcd) {
            int b = g * 32 + n_tile * 8 + xcd;
            acc += gpart[(size_t)b * 256 + t];
        }
    }
    if (t < 128) atomicAdd(&colsum[n_tile * 128 + t], acc);
    else         atomicAdd(&colsq[n_tile * 128 + t - 128], acc);
}

// ---------------- weights: W[K][N] fp32 -> Wt[N][K] bf16 ----------------
__global__ void k_cvt_wt(const float* __restrict__ W, unsigned short* __restrict__ Wt,
                         int K, int N) {
    int i = blockIdx.x * 256 + threadIdx.x;
    if (i < K * N) {
        int k = i / N, n = i - k * N;
        Wt[(size_t)n * K + k] = f32_to_bf16(W[i]);
    }
}

// ---------------- emb fp32 -> bf16 (row-major copy) ----------------
__global__ void k_cvt_emb(const float* __restrict__ e, unsigned short* __restrict__ o) {
    int i = blockIdx.x * 256 + threadIdx.x;
    if (i < 1000 * 256) o[i] = f32_to_bf16(e[i]);
}

// ---------------- BN coefficients: bn(x) = a*x + c ----------------
__global__ void k_bn_coeffs(const float* __restrict__ colsum, const float* __restrict__ colsq,
                            const float* __restrict__ g, const float* __restrict__ be,
                            float* __restrict__ a, float* __restrict__ c) {
    int f = blockIdx.x * 256 + threadIdx.x;
    if (f >= 512) return;
    float mu  = colsum[f] * (1.f / N_NODES);
    float var = colsq[f] * (1.f / N_NODES) - mu * mu;
    float ai  = g[f] * rsqrtf(var + 1e-5f);
    a[f] = ai;
    c[f] = be[f] - mu * ai;
}

// ---- layer 1 (factorized): pre1b[n] = bf16(b1 + sum over {n}+nbrs of embW[x[.]]) ----
__global__ __launch_bounds__(256) void k_gather_pre1(
    const unsigned short* __restrict__ embW, const int* __restrict__ x,
    const int* __restrict__ rowptr, const int* __restrict__ xsrc,
    const float* __restrict__ b1, unsigned short* __restrict__ pre1b,
    float* __restrict__ part) {
    __shared__ float red[2][3][512];
    int wave = threadIdx.x >> 6, lane = threadIdx.x & 63;
    float4 bl = ((const float4*)b1)[lane * 2], bh = ((const float4*)b1)[lane * 2 + 1];
    float ssum[8] = {}, ssq[8] = {};
    for (int node = blockIdx.x * 4 + wave; node < N_NODES; node += GP1_BLOCKS * 4) {
        float acc[8] = { bl.x, bl.y, bl.z, bl.w, bh.x, bh.y, bh.z, bh.w };
        int j0 = rowptr[node], j1 = rowptr[node + 1];
        int cnt = j1 - j0;
        int r_cur = x[node];
        int r_nxt = (cnt > 0) ? xsrc[j0] : 0;
        for (int t = 0; t <= cnt; ++t) {
            uint4 raw = ((const uint4*)(embW + (size_t)r_cur * 512))[lane];
            int r_follow = (t + 1 < cnt) ? xsrc[j0 + t + 1] : 0;
            acc[0] += bf_lo(raw.x); acc[1] += bf_hi(raw.x);
            acc[2] += bf_lo(raw.y); acc[3] += bf_hi(raw.y);
            acc[4] += bf_lo(raw.z); acc[5] += bf_hi(raw.z);
            acc[6] += bf_lo(raw.w); acc[7] += bf_hi(raw.w);
            r_cur = r_nxt; r_nxt = r_follow;
        }
        U16x4 o0{ f32_to_bf16(acc[0]), f32_to_bf16(acc[1]), f32_to_bf16(acc[2]), f32_to_bf16(acc[3]) };
        U16x4 o1{ f32_to_bf16(acc[4]), f32_to_bf16(acc[5]), f32_to_bf16(acc[6]), f32_to_bf16(acc[7]) };
        ((U16x4*)pre1b)[(size_t)node * 128 + lane * 2]     = o0;
        ((U16x4*)pre1b)[(size_t)node * 128 + lane * 2 + 1] = o1;
#pragma unroll
        for (int j2 = 0; j2 < 8; ++j2) { ssum[j2] += acc[j2]; ssq[j2] += acc[j2] * acc[j2]; }
    }
    if (wave != 0) {
#pragma unroll
        for (int j2 = 0; j2 < 8; ++j2) {
            red[0][wave - 1][lane * 8 + j2] = ssum[j2];
            red[1][wave - 1][lane * 8 + j2] = ssq[j2];
        }
    }
    __syncthreads();
    if (wave == 0) {
        float* p = part + (size_t)blockIdx.x * 1024;
#pragma unroll
        for (int j2 = 0; j2 < 8; ++j2) {
            int col = lane * 8 + j2;
            p[col]       = ssum[j2] + red[0][0][col] + red[0][1][col] + red[0][2][col];
            p[col + 512] = ssq[j2]  + red[1][0][col] + red[1][1][col] + red[1][2][col];
        }
    }
}

// ---- reduce GP1_BLOCKS x 1024 partials -> colsum1/colsq1 ----
__global__ __launch_bounds__(256) void k_red_stats(const float* __restrict__ part,
                                                   float* __restrict__ colsum,
                                                   float* __restrict__ colsq) {
    int t = threadIdx.x;
    float4 s = { 0.f, 0.f, 0.f, 0.f };
    int b0 = blockIdx.x * (GP1_BLOCKS / 32);
    for (int b = b0; b < b0 + GP1_BLOCKS / 32; ++b) {
        float4 v = ((const float4*)(part + (size_t)b * 1024))[t];
        s.x += v.x; s.y += v.y; s.z += v.z; s.w += v.w;
    }
    int o = t * 4;
    float* dst = (o < 512) ? (colsum + o) : (colsq + o - 512);
    atomicAdd(dst + 0, s.x); atomicAdd(dst + 1, s.y);
    atomicAdd(dst + 2, s.z); atomicAdd(dst + 3, s.w);
}

// ------- layer-2 aggregate (gather) -------
__global__ __launch_bounds__(256) void k_gather2(
    const unsigned short* __restrict__ pre1b, const int* __restrict__ rowptr,
    const int* __restrict__ srcs, const float* __restrict__ a1,
    const float* __restrict__ c1, unsigned short* __restrict__ agg2b) {
    int wave = threadIdx.x >> 6, lane = threadIdx.x & 63;
    int node = blockIdx.x * 4 + wave;
    if (node >= N_NODES) return;
    float4 aa0 = ((const float4*)a1)[lane * 2], aa1 = ((const float4*)a1)[lane * 2 + 1];
    float4 cc0 = ((const float4*)c1)[lane * 2], cc1 = ((const float4*)c1)[lane * 2 + 1];
    float acc[8] = {};
    int j0 = rowptr[node], j1 = rowptr[node + 1];
    int cnt = j1 - j0;
    int s_cur = node;
    int s_nxt = (cnt > 0) ? srcs[j0] : 0;
    for (int t = 0; t <= cnt; ++t) {
        uint4 raw = ((const uint4*)(pre1b + (size_t)s_cur * 512))[lane];
        int s_follow = (t + 1 < cnt) ? srcs[j0 + t + 1] : 0;
        acc[0] += fmaxf(fmaf(aa0.x, bf_lo(raw.x), cc0.x), 0.f);
        acc[1] += fmaxf(fmaf(aa0.y, bf_hi(raw.x), cc0.y), 0.f);
        acc[2] += fmaxf(fmaf(aa0.z, bf_lo(raw.y), cc0.z), 0.f);
        acc[3] += fmaxf(fmaf(aa0.w, bf_hi(raw.y), cc0.w), 0.f);
        acc[4] += fmaxf(fmaf(aa1.x, bf_lo(raw.z), cc1.x), 0.f);
        acc[5] += fmaxf(fmaf(aa1.y, bf_hi(raw.z), cc1.y), 0.f);
        acc[6] += fmaxf(fmaf(aa1.z, bf_lo(raw.w), cc1.z), 0.f);
        acc[7] += fmaxf(fmaf(aa1.w, bf_hi(raw.w), cc1.w), 0.f);
        s_cur = s_nxt; s_nxt = s_follow;
    }
    U16x4 o0{ f32_to_bf16(acc[0]), f32_to_bf16(acc[1]), f32_to_bf16(acc[2]), f32_to_bf16(acc[3]) };
    U16x4 o1{ f32_to_bf16(acc[4]), f32_to_bf16(acc[5]), f32_to_bf16(acc[6]), f32_to_bf16(acc[7]) };
    ((U16x4*)agg2b)[(size_t)node * 128 + lane * 2]     = o0;
    ((U16x4*)agg2b)[(size_t)node * 128 + lane * 2 + 1] = o1;
}

// ---------------- graph segment starts from sorted batch ----------------
__global__ void k_seg_starts(const int* __restrict__ batch, int* __restrict__ starts) {
    int i = blockIdx.x * 256 + threadIdx.x;
    if (i >= N_NODES) return;
    int b = batch[i];
    if (i == 0) {
        for (int g = 0; g <= b; ++g) starts[g] = 0;
    } else {
        int p = batch[i - 1];
        for (int g = p + 1; g <= b; ++g) starts[g] = i;
    }
    if (i == N_NODES - 1) {
        for (int g = b + 1; g <= N_GRAPHS; ++g) starts[g] = N_NODES;
    }
}

// ------- pooling -------
__global__ __launch_bounds__(256) void k_pool(const unsigned short* __restrict__ pre2b,
                                              const int* __restrict__ starts,
                                              const float* __restrict__ a2,
                                              const float* __restrict__ c2,
                                              float* __restrict__ pooled) {
    __shared__ float red[3 * 512];
    int g = blockIdx.x;
    int wave = threadIdx.x >> 6, lane = threadIdx.x & 63;
    int s = starts[g], e = starts[g + 1];
    float4 aa0 = ((const float4*)a2)[lane * 2], aa1 = ((const float4*)a2)[lane * 2 + 1];
    float4 cc0 = ((const float4*)c2)[lane * 2], cc1 = ((const float4*)c2)[lane * 2 + 1];
    float acc[8] = {};
    for (int n = s + wave; n < e; n += 4) {
        uint4 raw = ((const uint4*)(pre2b + (size_t)n * 512))[lane];
        acc[0] += fmaxf(fmaf(aa0.x, bf_lo(raw.x), cc0.x), 0.f);
        acc[1] += fmaxf(fmaf(aa0.y, bf_hi(raw.x), cc0.y), 0.f);
        acc[2] += fmaxf(fmaf(aa0.z, bf_lo(raw.y), cc0.z), 0.f);
        acc[3] += fmaxf(fmaf(aa0.w, bf_hi(raw.y), cc0.w), 0.f);
        acc[4] += fmaxf(fmaf(aa1.x, bf_lo(raw.z), cc1.x), 0.f);
        acc[5] += fmaxf(fmaf(aa1.y, bf_hi(raw.z), cc1.y), 0.f);
        acc[6] += fmaxf(fmaf(aa1.z, bf_lo(raw.w), cc1.z), 0.f);
        acc[7] += fmaxf(fmaf(aa1.w, bf_hi(raw.w), cc1.w), 0.f);
    }
    if (wave != 0) {
#pragma unroll
        for (int j = 0; j < 8; ++j) red[(wave - 1) * 512 + lane * 8 + j] = acc[j];
    }
    __syncthreads();
    if (wave == 0) {
#pragma unroll
        for (int j = 0; j < 8; ++j)
            acc[j] += red[lane * 8 + j] + red[512 + lane * 8 + j] + red[1024 + lane * 8 + j];
        float inv = 1.f / fmaxf((float)(e - s), 1.f);
#pragma unroll
        for (int j = 0; j < 8; ++j) pooled[(size_t)g * 512 + lane * 8 + j] = acc[j] * inv;
    }
}

// ---------------- small MLP ----------------
__global__ __launch_bounds__(256) void k_mlp1(const float* __restrict__ pooled,
                                              const float* __restrict__ Wl1,
                                              const float* __restrict__ bl1,
                                              float* __restrict__ z) {
    __shared__ float sp[512];
    int i = blockIdx.x, j = threadIdx.x;
    sp[j]       = pooled[(size_t)i * 512 + j];
    sp[j + 256] = pooled[(size_t)i * 512 + 256 + j];
    __syncthreads();
    float acc = bl1[j];
#pragma unroll 4
    for (int k = 0; k < 512; ++k) acc = fmaf(sp[k], Wl1[(size_t)k * 256 + j], acc);
    z[(size_t)i * 256 + j] = fmaxf(acc, 0.f);
}

__global__ __launch_bounds__(128) void k_mlp2(const float* __restrict__ z,
                                              const float* __restrict__ Wl2,
                                              const float* __restrict__ bl2,
                                              float* __restrict__ out) {
    __shared__ float sz[256];
    int i = blockIdx.x, j = threadIdx.x;
    sz[j]       = z[(size_t)i * 256 + j];
    sz[j + 128] = z[(size_t)i * 256 + 128 + j];
    __syncthreads();
    float acc = bl2[j];
#pragma unroll 4
    for (int k = 0; k < 256; ++k) acc = fmaf(sz[k], Wl2[(size_t)k * 128 + j], acc);
    out[(size_t)i * 128 + j] = acc;
}

extern "C" void kernel_launch(void* const* d_in, const int* in_sizes, int n_in,
                              void* d_out, int out_size, void* d_ws, size_t ws_size,
                              hipStream_t stream) {
    const int*   x    = (const int*)d_in[0];
    const int*   ei   = (const int*)d_in[1];
    const int*   batch= (const int*)d_in[2];
    const float* emb  = (const float*)d_in[3];
    const float* W1   = (const float*)d_in[4];
    const float* b1   = (const float*)d_in[5];
    const float* g1   = (const float*)d_in[6];
    const float* be1  = (const float*)d_in[7];
    const float* W2   = (const float*)d_in[8];
    const float* b2   = (const float*)d_in[9];
    const float* g2   = (const float*)d_in[10];
    const float* be2  = (const float*)d_in[11];
    const float* Wl1  = (const float*)d_in[12];
    const float* bl1  = (const float*)d_in[13];
    const float* Wl2  = (const float*)d_in[14];
    const float* bl2  = (const float*)d_in[15];
    float* out = (float*)d_out;

    char* ws = (char*)d_ws;
    size_t o = 0;
    auto alloc = [&](size_t bytes) { char* p = ws + o; o += (bytes + 255) & ~(size_t)255; return p; };

    // ---- small persistent buffers (~21 MB) ----
    unsigned short* W1tb = (unsigned short*)alloc((size_t)512 * 256 * 2);
    unsigned short* W2tb = (unsigned short*)alloc((size_t)512 * 512 * 2);
    unsigned short* embB = (unsigned short*)alloc((size_t)1024 * 256 * 2);
    unsigned short* embW = (unsigned short*)alloc((size_t)1024 * 512 * 2);
    float* sums   = (float*)alloc(4 * 512 * 4);
    float* colsum1 = sums, *colsq1 = sums + 512, *colsum2 = sums + 1024, *colsq2 = sums + 1536;
    float* coeffs = (float*)alloc(4 * 512 * 4);
    float* a1 = coeffs, *c1 = coeffs + 512, *a2 = coeffs + 1024, *c2 = coeffs + 1536;
    int*   starts = (int*)alloc((N_GRAPHS + 1) * 4);
    float* pooled = (float*)alloc((size_t)N_GRAPHS * 512 * 4);
    float* zbuf   = (float*)alloc((size_t)N_GRAPHS * 256 * 4);
    int*   counts = (int*)alloc((size_t)N_NODES * 4);
    int*   rowptr = (int*)alloc((size_t)(N_NODES + 1) * 4);
    int*   cursor = (int*)alloc((size_t)N_NODES * 4);
    int*   srcs   = (int*)alloc((size_t)N_EDGES * 4);
    int*   xsrc   = (int*)alloc((size_t)N_EDGES * 4);
    int*   bsum   = (int*)alloc((size_t)NBLK * 4);
    int*   bpre   = (int*)alloc((size_t)NBLK * 4);
    float* part   = (float*)alloc((size_t)GP1_BLOCKS * 1024 * 4);   // 8 MB layer-1 stats partials
    float* gpart  = (float*)alloc((size_t)GEMM_BLOCKS * 256 * 4);   // 3.2 MB GEMM stats partials

    // ---- slotA (102.5 MB): agg2b(bf16, MPAD*512) ----
    unsigned short* agg2b = (unsigned short*)alloc((size_t)MPAD * 512 * 2);
    // ---- slotB (102.5 MB): pre1b -> pre2b (disjoint lifetimes) ----
    char* slotB = alloc((size_t)MPAD * 512 * 2);
    unsigned short* pre1b = (unsigned short*)slotB;
    unsigned short* pre2b = (unsigned short*)slotB;
    (void)ws_size; (void)in_sizes; (void)n_in; (void)out_size;

    // ---- CSR build (parallel 3-phase scan) ----
    k_zero_int<<<(N_NODES + 255) / 256, 256, 0, stream>>>(counts, N_NODES);
    k_zero_f<<<8, 256, 0, stream>>>(sums, 2048);
    k_hist<<<(N_EDGES + 255) / 256, 256, 0, stream>>>(ei, counts);
    k_blocksum<<<NBLK, SB, 0, stream>>>(counts, bsum);
    k_scan_bsum<<<1, 512, 0, stream>>>(bsum, bpre);
    k_scan_final<<<NBLK, SB, 0, stream>>>(counts, bpre, rowptr, cursor);
    k_fill<<<(N_EDGES + 255) / 256, 256, 0, stream>>>(ei, x, cursor, srcs, xsrc);

    // ---- weight / table prep ----
    k_cvt_wt<<<(256 * 512 + 255) / 256, 256, 0, stream>>>(W1, W1tb, 256, 512);
    k_cvt_wt<<<(512 * 512 + 255) / 256, 256, 0, stream>>>(W2, W2tb, 512, 512);
    k_cvt_emb<<<1000, 256, 0, stream>>>(emb, embB);
    k_gemm_bias_stats<256, false><<<32, 256, 0, stream>>>(
        embB, W1tb, nullptr, embW, nullptr, 1024);

    // ---- layer 1 (gather-aggregate of embW rows; stats fused via partials) ----
    k_gather_pre1<<<GP1_BLOCKS, 256, 0, stream>>>(embW, x, rowptr, xsrc, b1, pre1b, part);
    k_red_stats<<<32, 256, 0, stream>>>(part, colsum1, colsq1);
    k_bn_coeffs<<<2, 256, 0, stream>>>(colsum1, colsq1, g1, be1, a1, c1);

    // ---- layer 2 ----
    k_gather2<<<(N_NODES + 3) / 4, 256, 0, stream>>>(pre1b, rowptr, srcs, a1, c1, agg2b);
    k_gemm_bias_stats<512, true><<<GEMM_BLOCKS, 256, 0, stream>>>(
        agg2b, W2tb, b2, pre2b, gpart, N_NODES);
    k_red_gemm<<<32, 256, 0, stream>>>(gpart, colsum2, colsq2);
    k_bn_coeffs<<<2, 256, 0, stream>>>(colsum2, colsq2, g2, be2, a2, c2);

    // ---- pooling + MLP ----
    k_seg_starts<<<(N_NODES + 255) / 256, 256, 0, stream>>>(batch, starts);
    k_pool<<<N_GRAPHS, 256, 0, stream>>>(pre2b, starts, a2, c2, pooled);
    k_mlp1<<<N_GRAPHS, 256, 0, stream>>>(pooled, Wl1, bl1, zbuf);
    k_mlp2<<<N_GRAPHS, 128, 0, stream>>>(zbuf, Wl2, bl2, out);
}